// Round 9
// baseline (198.410 us; speedup 1.0000x reference)
//
#include <hip/hip_runtime.h>
#include <hip/hip_bf16.h>

typedef __hip_bfloat16 bf16;
typedef __attribute__((ext_vector_type(8))) short bf16x8;
typedef __attribute__((ext_vector_type(4))) float f32x4;
#define DEV __device__ __forceinline__

constexpr int SEQ  = 4096;
constexpr int NB   = 4;
constexpr int NTOK = NB * SEQ;          // 16384 tokens
constexpr float EPS = 1e-5f;
constexpr int NCH = 32;                 // scan chunk length
constexpr int NCHUNK = SEQ / NCH;       // 128 chunks/seq
constexpr float LOG2E = 1.44269504f;

// ---------------- workspace layout (float offsets) ----------------
constexpr int OFF_WDT  = 0;                    // f32 [8][256] dt_proj^T
constexpr int OFF_WB   = 2048;                 // bf16 weight area (151552 shorts)
constexpr int WB_IP = 0;                       // [128][64]
constexpr int WB_WP = 8192;                    // [128][64]
constexpr int WB_FP = 16384;                   // [128][128]
constexpr int WB_PR = 32768;                   // [512][128]
constexpr int WB_MO = 98304;                   // [128][256]
constexpr int WB_OP = 131072;                  // [64][128]
constexpr int WB_XP = 139264;                  // [48][256] (40 real + 8 zero rows)
constexpr int WB_TOT = 151552;
constexpr int OFF_XDBL = OFF_WB + WB_TOT / 2;        // f32 [NTOK][40]
constexpr int OFF_R1   = OFF_XDBL + NTOK * 40;       // (unused)
constexpr int OFF_WSW  = OFF_R1   + 1048576;         // bf16 NTOK*128
constexpr int OFF_U    = OFF_WSW  + 1048576;         // bf16 NTOK*128
constexpr int OFF_R2   = OFF_U    + 1048576;         // xpre
constexpr int OFF_SILUZ= OFF_R2   + 2097152;         // bf16 NTOK*256
constexpr int OFF_XC   = OFF_SILUZ+ 2097152;         // bf16 NTOK*256
constexpr int OFF_G    = OFF_XC   + 2097152;         // bf16 NTOK*256
constexpr int OFF_FLAG = OFF_G    + 2097152;         // int dtype flag
constexpr int OFF_SUMM = OFF_FLAG + 16;              // f32 [64][NCHUNK][256][2]
constexpr int OFF_HIN  = OFF_SUMM + 64 * NCHUNK * 256 * 2;  // f32 [64][NCHUNK][256]
constexpr int OFF_PLOC = OFF_HIN  + 64 * NCHUNK * 256;      // f32 [NTOK][256]
constexpr int OFF_CUMD = OFF_PLOC + NTOK * 256;             // f32 [NTOK][256]

DEV float b2f(bf16 x) { return __bfloat162float(x); }
DEV bf16 f2b(float x) { return __float2bfloat16(x); }
DEV short shof(bf16 h) { short s; __builtin_memcpy(&s, &h, 2); return s; }
DEV float ldin(const void* p, int i, int f) {
  return f ? ((const float*)p)[i] : b2f(((const bf16*)p)[i]);
}
DEV unsigned pack2(float a, float b) {
  bf16 ha = f2b(a), hb = f2b(b);
  unsigned short ua, ub;
  __builtin_memcpy(&ua, &ha, 2); __builtin_memcpy(&ub, &hb, 2);
  return (unsigned)ua | ((unsigned)ub << 16);
}
DEV float lo16f(unsigned u) { return __int_as_float((int)(u << 16)); }
DEV float hi16f(unsigned u) { return __int_as_float((int)(u & 0xffff0000u)); }
template<int CTRL>
DEV float dpp_add(float v) {
  int r = __builtin_amdgcn_update_dpp(0, __float_as_int(v), CTRL, 0xF, 0xF, false);
  return v + __int_as_float(r);
}
DEV float exp2f_fast(float a) { return __builtin_amdgcn_exp2f(a); }
DEV float softplus(float a) {
  return (a > 20.f) ? a : __logf(1.f + exp2f_fast(a * LOG2E));
}
DEV float silu(float a) { return a / (1.f + __expf(-a)); }

// ---------------- prep: inline dtype detect + bf16 weight copies + WDT f32 ----------------
DEV void cpw(int e, int base, int count, const void* __restrict__ src,
             bf16* __restrict__ wb, int f) {
  int r = e - base;
  if (r >= 0 && r < count) wb[base + r] = f2b(ldin(src, r, f));
}
__global__ __launch_bounds__(256) void prep_k(
    const void* __restrict__ w_ip, const void* __restrict__ w_wp, const void* __restrict__ w_fp,
    const void* __restrict__ w_pr, const void* __restrict__ w_mo, const void* __restrict__ w_op,
    const void* __restrict__ w_x,  const void* __restrict__ w_dt,
    const void* __restrict__ x, float* __restrict__ wsf, int* __restrict__ flagp)
{
  __shared__ int cnt;
  if (threadIdx.x == 0) cnt = 0;
  __syncthreads();
  {
    float v = b2f(((const bf16*)x)[threadIdx.x]);
    int ok = (v == v) && fabsf(v) > 1e-4f && fabsf(v) < 100.f;
    atomicAdd(&cnt, ok);
  }
  __syncthreads();
  int f = (cnt > 204) ? 0 : 1;
  if (blockIdx.x == 0 && threadIdx.x == 0) *flagp = f;

  int e = blockIdx.x * 256 + threadIdx.x;   // 592*256 covers 151552
  bf16* wb = (bf16*)(wsf + OFF_WB);
  cpw(e, WB_IP, 8192,  w_ip, wb, f);
  cpw(e, WB_WP, 8192,  w_wp, wb, f);
  cpw(e, WB_FP, 16384, w_fp, wb, f);
  cpw(e, WB_PR, 65536, w_pr, wb, f);
  cpw(e, WB_MO, 32768, w_mo, wb, f);
  cpw(e, WB_OP, 8192,  w_op, wb, f);
  {
    int r = e - WB_XP;
    if (r >= 0 && r < 12288) wb[WB_XP + r] = (r < 10240) ? f2b(ldin(w_x, r, f)) : f2b(0.f);
  }
  if (e < 2048) {
    int r = e >> 8, d = e & 255;
    wsf[OFF_WDT + e] = ldin(w_dt, d * 8 + r, f);
  }
}

// ---------------- fm: rms1 + ip/wp GEMMs + fp GEMM + in_proj GEMM (512 thr / 8 waves) ----------------
__global__ __launch_bounds__(512) void fm_k(
    const void* __restrict__ x, const void* __restrict__ w1, const float* __restrict__ wsf,
    const void* __restrict__ b_ip, const void* __restrict__ b_wp, const void* __restrict__ b_fp,
    bf16* __restrict__ wsw, bf16* __restrict__ u, bf16* __restrict__ xpre,
    bf16* __restrict__ siluz, const int* __restrict__ flagp)
{
  // phase A: xn [0,4608) t1 [4608,13312) ul [13312,22016) wswl [22016,30208)
  // phase B (after GEMM3 frag loads + barrier): xzl [0,33280) aliases all of phase A
  __shared__ __align__(16) char smem[33280];
  short* xn   = (short*)smem;             // [32][72]
  short* t1   = (short*)(smem + 4608);    // [32][136]
  short* ul   = (short*)(smem + 13312);   // [32][136]
  short* wswl = (short*)(smem + 22016);   // [32][128]
  short* xzl  = (short*)smem;             // [32][520] (512 + 8 pad)

  const int f = *flagp;
  const int tid = threadIdx.x;
  const int tok0 = blockIdx.x * 32;
  {  // rms1: 16 threads/token, 4 ch each
    const int token = tid >> 4, r = tid & 15;
    float v[4]; float ss = 0.f;
    #pragma unroll
    for (int k = 0; k < 4; ++k) {
      v[k] = ldin(x, (tok0 + token) * 64 + r * 4 + k, f);
      ss += v[k] * v[k];
    }
    ss += __shfl_xor(ss, 1, 16); ss += __shfl_xor(ss, 2, 16);
    ss += __shfl_xor(ss, 4, 16); ss += __shfl_xor(ss, 8, 16);
    float sc = rsqrtf(ss * (1.f / 64.f) + EPS);
    unsigned* dst = (unsigned*)xn + token * 36 + r * 2;
    #pragma unroll
    for (int k = 0; k < 2; ++k) {
      int i = r * 4 + k * 2;
      dst[k] = pack2(v[k*2] * sc * ldin(w1, i, f), v[k*2+1] * sc * ldin(w1, i + 1, f));
    }
  }
  __syncthreads();
  const int lane = tid & 63, m = lane & 15, q = lane >> 4;
  const int w = tid >> 6;
  {  // GEMM1/1b: K=64, N=128 each. waves 0-3 -> Wip (t1), 4-7 -> Wwp (wswl); 2 nt each
    const int wt = w >> 2, ng = w & 3;
    const bf16* W = (const bf16*)(wsf + OFF_WB) + (wt ? WB_WP : WB_IP);
    const void* bia = wt ? b_wp : b_ip;
    bf16x8 a[2][2];
    #pragma unroll
    for (int mt = 0; mt < 2; ++mt)
      #pragma unroll
      for (int kk = 0; kk < 2; ++kk)
        a[mt][kk] = *(const bf16x8*)&xn[(mt * 16 + m) * 72 + kk * 32 + q * 8];
    #pragma unroll
    for (int nti = 0; nti < 2; ++nti) {
      int nt = ng * 2 + nti;
      int n = nt * 16 + m;
      f32x4 acc[2] = {{0,0,0,0},{0,0,0,0}};
      #pragma unroll
      for (int kk = 0; kk < 2; ++kk) {
        bf16x8 b = *(const bf16x8*)(W + (nt * 16 + m) * 64 + kk * 32 + q * 8);
        #pragma unroll
        for (int mt = 0; mt < 2; ++mt)
          acc[mt] = __builtin_amdgcn_mfma_f32_16x16x32_bf16(a[mt][kk], b, acc[mt], 0, 0, 0);
      }
      float bv = ldin(bia, n, f);
      #pragma unroll
      for (int mt = 0; mt < 2; ++mt)
        #pragma unroll
        for (int r = 0; r < 4; ++r) {
          float v = acc[mt][r] + bv;
          int row = mt * 16 + q * 4 + r;
          if (wt) wswl[row * 128 + n] = shof(f2b(silu(v)));
          else    t1[row * 136 + n] = shof(f2b(v));
        }
    }
  }
  __syncthreads();
  {  // wsw coalesced copy-out
    int row = tid >> 4, c8 = (tid & 15) * 8;
    uint4 v = *(const uint4*)&wswl[row * 128 + c8];
    *(uint4*)(wsw + (tok0 + row) * 128 + c8) = v;
  }
  {  // GEMM2: u = t1@Wfp^T + b_fp. K=128, N=128; wave w -> nt w (LDS only)
    const bf16* WF = (const bf16*)(wsf + OFF_WB) + WB_FP;
    bf16x8 a[2][4];
    #pragma unroll
    for (int mt = 0; mt < 2; ++mt)
      #pragma unroll
      for (int kk = 0; kk < 4; ++kk)
        a[mt][kk] = *(const bf16x8*)&t1[(mt * 16 + m) * 136 + kk * 32 + q * 8];
    {
      int nt = w;
      int n = nt * 16 + m;
      f32x4 acc[2] = {{0,0,0,0},{0,0,0,0}};
      #pragma unroll
      for (int kk = 0; kk < 4; ++kk) {
        bf16x8 b = *(const bf16x8*)(WF + (nt * 16 + m) * 128 + kk * 32 + q * 8);
        #pragma unroll
        for (int mt = 0; mt < 2; ++mt)
          acc[mt] = __builtin_amdgcn_mfma_f32_16x16x32_bf16(a[mt][kk], b, acc[mt], 0, 0, 0);
      }
      float bv = ldin(b_fp, n, f);
      #pragma unroll
      for (int mt = 0; mt < 2; ++mt)
        #pragma unroll
        for (int r = 0; r < 4; ++r)
          ul[(mt * 16 + q * 4 + r) * 136 + n] = shof(f2b(acc[mt][r] + bv));
    }
  }
  __syncthreads();
  {  // u coalesced copy-out
    int row = tid >> 4, c8 = (tid & 15) * 8;
    uint4 v = *(const uint4*)&ul[row * 136 + c8];
    *(uint4*)(u + (tok0 + row) * 128 + c8) = v;
  }
  {  // GEMM3: xz = u@Wpr^T. K=128, N=512; wave w -> nt [4w, 4w+4); results -> xzl
    const bf16* WP = (const bf16*)(wsf + OFF_WB) + WB_PR;
    bf16x8 a[2][4];
    #pragma unroll
    for (int mt = 0; mt < 2; ++mt)
      #pragma unroll
      for (int kk = 0; kk < 4; ++kk)
        a[mt][kk] = *(const bf16x8*)&ul[(mt * 16 + m) * 136 + kk * 32 + q * 8];
    __syncthreads();   // all ul/t1/xn reads done; xzl alias becomes safe
    #pragma unroll
    for (int nti = 0; nti < 4; ++nti) {
      int nt = w * 4 + nti;
      int n = nt * 16 + m;
      f32x4 acc[2] = {{0,0,0,0},{0,0,0,0}};
      #pragma unroll
      for (int kk = 0; kk < 4; ++kk) {
        bf16x8 b = *(const bf16x8*)(WP + (nt * 16 + m) * 128 + kk * 32 + q * 8);
        #pragma unroll
        for (int mt = 0; mt < 2; ++mt)
          acc[mt] = __builtin_amdgcn_mfma_f32_16x16x32_bf16(a[mt][kk], b, acc[mt], 0, 0, 0);
      }
      #pragma unroll
      for (int mt = 0; mt < 2; ++mt)
        #pragma unroll
        for (int r = 0; r < 4; ++r) {
          int row = mt * 16 + q * 4 + r;
          float v = acc[mt][r];
          xzl[row * 520 + n] = shof(f2b(n < 256 ? v : silu(v)));
        }
    }
  }
  __syncthreads();
  {  // xz coalesced copy-out
    #pragma unroll
    for (int k = 0; k < 4; ++k) {
      int chunk = tid + k * 512;
      int row = chunk >> 6, seg = chunk & 63;
      uint4 v = *(const uint4*)&xzl[row * 520 + seg * 8];
      int n0 = seg * 8;
      if (n0 < 256) *(uint4*)(xpre + (tok0 + row) * 256 + n0) = v;
      else          *(uint4*)(siluz + (tok0 + row) * 256 + (n0 - 256)) = v;
    }
  }
}

// ---------------- conv (depthwise w4 + silu) + x_proj MFMA -> xc, xdbl ----------------
__global__ __launch_bounds__(256) void conv_k(
    const bf16* __restrict__ xpre, const void* __restrict__ cw, const void* __restrict__ cb,
    const float* __restrict__ wsf, bf16* __restrict__ xc, float* __restrict__ xdbl,
    const int* __restrict__ flagp)
{
  __shared__ short xh[35 * 256];
  __shared__ short cs[32 * 264];
  const int f = *flagp;
  const int tid = threadIdx.x;
  const int tok0 = blockIdx.x * 32;
  const bool seqstart = (tok0 & (SEQ - 1)) == 0;
  for (int c = tid; c < 1120; c += 256) {
    int e0 = c * 8;
    int tt = e0 >> 8, i = e0 & 255;
    int gtok = tok0 + tt - 3;
    uint4* dst = (uint4*)(xh + e0);
    if (gtok >= 0 && !(seqstart && tt < 3)) *dst = *(const uint4*)(xpre + gtok * 256 + i);
    else                                    *dst = make_uint4(0, 0, 0, 0);
  }
  __syncthreads();
  {
    const int ch0 = (tid & 63) * 4;
    const int t0 = (tid >> 6) * 8;
    float w4[4][4], cb4[4];
    #pragma unroll
    for (int c = 0; c < 4; ++c) {
      cb4[c] = ldin(cb, ch0 + c, f);
      #pragma unroll
      for (int k = 0; k < 4; ++k) w4[c][k] = ldin(cw, (ch0 + c) * 4 + k, f);
    }
    float win[11][4];
    #pragma unroll
    for (int r = 0; r < 11; ++r) {
      uint2 v = *(const uint2*)&xh[(t0 + r) * 256 + ch0];
      win[r][0] = lo16f(v.x); win[r][1] = hi16f(v.x);
      win[r][2] = lo16f(v.y); win[r][3] = hi16f(v.y);
    }
    #pragma unroll
    for (int t = 0; t < 8; ++t) {
      unsigned pk[2];
      #pragma unroll
      for (int cp = 0; cp < 2; ++cp) {
        float o[2];
        #pragma unroll
        for (int ci = 0; ci < 2; ++ci) {
          int c = cp * 2 + ci;
          float acc = cb4[c];
          #pragma unroll
          for (int k = 0; k < 4; ++k) acc = fmaf(win[t + k][c], w4[c][k], acc);
          o[ci] = silu(acc);
        }
        pk[cp] = pack2(o[0], o[1]);
      }
      uint2 pv = make_uint2(pk[0], pk[1]);
      *(uint2*)&cs[(t0 + t) * 264 + ch0] = pv;
      *(uint2*)(xc + (tok0 + t0 + t) * 256 + ch0) = pv;
    }
  }
  __syncthreads();
  const int w = tid >> 6;
  if (w < 2) {
    const bf16* Wx = (const bf16*)(wsf + OFF_WB) + WB_XP;
    const int lane = tid & 63, m = lane & 15, quad = lane >> 4;
    f32x4 acc[3] = {{0,0,0,0},{0,0,0,0},{0,0,0,0}};
    #pragma unroll
    for (int k0 = 0; k0 < 256; k0 += 32) {
      bf16x8 af = *(const bf16x8*)&cs[(w * 16 + m) * 264 + k0 + quad * 8];
      #pragma unroll
      for (int nt = 0; nt < 3; ++nt) {
        bf16x8 bfr = *(const bf16x8*)(Wx + (nt * 16 + m) * 256 + k0 + quad * 8);
        acc[nt] = __builtin_amdgcn_mfma_f32_16x16x32_bf16(af, bfr, acc[nt], 0, 0, 0);
      }
    }
    #pragma unroll
    for (int nt = 0; nt < 3; ++nt) {
      int n = nt * 16 + m;
      if (n < 40) {
        #pragma unroll
        for (int r = 0; r < 4; ++r)
          xdbl[(tok0 + w * 16 + quad * 4 + r) * 40 + n] = acc[nt][r];
      }
    }
  }
}

// ---------------- scan pass F: local chunk scan + p_local/cumdlt/summary ----------------
// h_t = h_local_t + 2^(Aval2*cumdlt_t)*h_init (linear superposition). F computes the
// local chain (serial), its C-dot p_local, the inclusive delta prefix cumdlt, and the
// chunk summary (dA_total, h_local_final) for scanB.
__global__ __launch_bounds__(256) void scanF_k(
    const float* __restrict__ xdbl, const bf16* __restrict__ xc,
    const void* __restrict__ A_log, const void* __restrict__ dt_b,
    const float* __restrict__ WDT, float* __restrict__ summ,
    float* __restrict__ ploc, float* __restrict__ cumd, const int* __restrict__ flagp)
{
  const int f = *flagp;
  const int tid = threadIdx.x;
  const int bb = blockIdx.x >> 2, dgsup = blockIdx.x & 3, c = blockIdx.y;
  const int dgsub = tid >> 6, lane = tid & 63, dl = lane >> 2, squad = lane & 3;
  const int dg = dgsup * 4 + dgsub;
  const int bxOld = bb * 16 + dg;
  const int d_comp = dg * 16 + dl;
  const int bd = tid & 63;
  const int d_stg = dgsup * 64 + bd;
  const int bdc = dgsub * 16 + dl;
  const int tok_base = bb * SEQ + c * NCH;

  __shared__ float dt_l[NCH * 8];     // 1 KB
  __shared__ float dx_l[16 * 64 * 2]; // 8 KB
  __shared__ float Bp[16 * 16];       // 1 KB
  __shared__ float Cp[16 * 16];       // 1 KB
  __shared__ float pg_l[16 * 64];     // 4 KB
  __shared__ float cd_l[16 * 64];     // 4 KB

  float Aval2[4];
  #pragma unroll
  for (int j = 0; j < 4; ++j)
    Aval2[j] = -__expf(ldin(A_log, d_comp * 16 + squad * 4 + j, f)) * LOG2E;
  const float dtb_stg = ldin(dt_b, d_stg, f);
  float wdt[8];
  #pragma unroll
  for (int r = 0; r < 8; ++r) wdt[r] = WDT[r * 256 + d_stg];

  float h[4] = {0.f, 0.f, 0.f, 0.f};
  float sdlt = 0.f;

  if (tid < 64)   // dt_l: whole chunk, [t][8]; 2 threads/token
    *(float4*)(dt_l + tid * 4) = *(const float4*)(xdbl + (tok_base + (tid >> 1)) * 40 + (tid & 1) * 4);

  #pragma unroll 1
  for (int half = 0; half < 2; ++half) {
    const int tb = half * 16;
    __syncthreads();   // prev-half pg/cd reads done; dt_l ready for half 0
    {   // B/C planes: [t-half][s]
      int tl = tid >> 4, s = tid & 15;
      int tok = tok_base + tb + tl;
      Bp[tid] = xdbl[tok * 40 + 8 + s];
      Cp[tid] = xdbl[tok * 40 + 24 + s];
    }
    #pragma unroll
    for (int k = 0; k < 4; ++k) {   // dx: [t-half][bd]
      int tl = (tid >> 6) + k * 4;
      int tok = tok_base + tb + tl;
      const float* dtr = dt_l + (tb + tl) * 8;
      float a = dtb_stg;
      #pragma unroll
      for (int r = 0; r < 8; ++r) a = fmaf(dtr[r], wdt[r], a);
      float dlt = softplus(a);
      float xcv = b2f(xc[tok * 256 + d_stg]);
      *(float2*)(dx_l + (tl * 64 + bd) * 2) = make_float2(dlt, dlt * xcv);
    }
    __syncthreads();

    #pragma unroll 8
    for (int tl = 0; tl < 16; ++tl) {
      float2 dx = *(const float2*)(dx_l + (tl * 64 + bdc) * 2);   // quad-broadcast
      float4 B4 = *(const float4*)(Bp + tl * 16 + squad * 4);
      float Bv[4] = {B4.x, B4.y, B4.z, B4.w};
      #pragma unroll
      for (int j = 0; j < 4; ++j) {
        float dA = exp2f_fast(dx.x * Aval2[j]);
        h[j] = fmaf(dA, h[j], dx.y * Bv[j]);
      }
      sdlt += dx.x;
      float4 C4 = *(const float4*)(Cp + tl * 16 + squad * 4);
      float p = h[0] * C4.x;
      p = fmaf(h[1], C4.y, p);
      p = fmaf(h[2], C4.z, p);
      p = fmaf(h[3], C4.w, p);
      p = dpp_add<0xB1>(p);   // quad xor1
      p = dpp_add<0x4E>(p);   // quad xor2
      if (squad == 0) { pg_l[tl * 64 + bdc] = p; cd_l[tl * 64 + bdc] = sdlt; }
    }
    __syncthreads();
    #pragma unroll
    for (int k = 0; k < 4; ++k) {   // coalesced p_local / cumdlt out
      int tl = (tid >> 6) + k * 4;
      int tok = tok_base + tb + tl;
      ploc[tok * 256 + d_stg] = pg_l[tl * 64 + bd];
      cumd[tok * 256 + d_stg] = cd_l[tl * 64 + bd];
    }
  }

  float* dst = summ + ((bxOld * NCHUNK + c) * 256 + dl * 16 + squad * 4) * 2;
  *(float4*)(dst)     = make_float4(exp2f_fast(Aval2[0] * sdlt), h[0],
                                    exp2f_fast(Aval2[1] * sdlt), h[1]);
  *(float4*)(dst + 4) = make_float4(exp2f_fast(Aval2[2] * sdlt), h[2],
                                    exp2f_fast(Aval2[3] * sdlt), h[3]);
}

// phase B: exclusive scan over chunk summaries, 16-deep load batching
__global__ __launch_bounds__(256) void scanB_k(const float* __restrict__ summ, float* __restrict__ hinit) {
  int bx = blockIdx.x, qq = threadIdx.x;
  float h = 0.f;
  for (int c0 = 0; c0 < NCHUNK; c0 += 16) {
    float2 sv[16];
    #pragma unroll
    for (int k = 0; k < 16; ++k)
      sv[k] = *(const float2*)(summ + ((bx * NCHUNK + c0 + k) * 256 + qq) * 2);
    #pragma unroll
    for (int k = 0; k < 16; ++k) {
      hinit[(bx * NCHUNK + c0 + k) * 256 + qq] = h;
      h = fmaf(sv[k].x, h, sv[k].y);
    }
  }
}

// ---------------- scan pass C: parallel correction + gating ----------------
// g[t,d] = (p_local[t,d] + sum_s C[t,s]*2^(Aval2_s*cumdlt[t,d])*hinit[s,d] + xc*D) * siluz
// No t->t dependency: pure throughput.
__global__ __launch_bounds__(256) void scanC_k(
    const float* __restrict__ xdbl, const bf16* __restrict__ xc, const bf16* __restrict__ siluz,
    const void* __restrict__ A_log, const void* __restrict__ D_par,
    const float* __restrict__ hinit, const float* __restrict__ ploc,
    const float* __restrict__ cumd, bf16* __restrict__ g, const int* __restrict__ flagp)
{
  const int f = *flagp;
  const int tid = threadIdx.x;
  const int bb = blockIdx.x >> 2, dgsup = blockIdx.x & 3, c = blockIdx.y;
  const int dgsub = tid >> 6, lane = tid & 63, dl = lane >> 2, squad = lane & 3;
  const int dg = dgsup * 4 + dgsub;
  const int bxOld = bb * 16 + dg;
  const int d_comp = dg * 16 + dl;
  const int bd = tid & 63;
  const int d_stg = dgsup * 64 + bd;
  const int bdc = dgsub * 16 + dl;
  const int tok_base = bb * SEQ + c * NCH;

  __shared__ float Cp[NCH * 16];      // 2 KB (full chunk)
  __shared__ float cd_l[NCH * 64];    // 8 KB
  __shared__ float g_l[NCH * 64];     // 8 KB

  float Aval2[4];
  #pragma unroll
  for (int j = 0; j < 4; ++j)
    Aval2[j] = -__expf(ldin(A_log, d_comp * 16 + squad * 4 + j, f)) * LOG2E;
  const float Dp_stg = ldin(D_par, d_stg, f);

  float4 hv = *(const float4*)(hinit + (bxOld * NCHUNK + c) * 256 + dl * 16 + squad * 4);

  #pragma unroll
  for (int k = 0; k < 2; ++k) {   // C plane: 32 tok x 16 s
    int e = tid + k * 256;
    int tl = e >> 4, s = e & 15;
    Cp[e] = xdbl[(tok_base + tl) * 40 + 24 + s];
  }
  #pragma unroll
  for (int k = 0; k < 8; ++k) {   // cumdlt: [t][bd] coalesced
    int tl = (tid >> 6) + k * 4;
    cd_l[tl * 64 + bd] = cumd[(tok_base + tl) * 256 + d_stg];
  }
  __syncthreads();

  #pragma unroll 8
  for (int tl = 0; tl < NCH; ++tl) {
    float cum = cd_l[tl * 64 + bdc];                  // quad-broadcast
    float4 C4 = *(const float4*)(Cp + tl * 16 + squad * 4);
    float p =      C4.x * exp2f_fast(cum * Aval2[0]) * hv.x;
    p = fmaf(C4.y * exp2f_fast(cum * Aval2[1]), hv.y, p);
    p = fmaf(C4.z * exp2f_fast(cum * Aval2[2]), hv.z, p);
    p = fmaf(C4.w * exp2f_fast(cum * Aval2[3]), hv.w, p);
    p = dpp_add<0xB1>(p);   // quad xor1
    p = dpp_add<0x4E>(p);   // quad xor2
    if (squad == 0) g_l[tl * 64 + bdc] = p;
  }
  __syncthreads();

  #pragma unroll
  for (int k = 0; k < 8; ++k) {
    int tl = (tid >> 6) + k * 4;
    int tok = tok_base + tl;
    float pf = ploc[tok * 256 + d_stg] + g_l[tl * 64 + bd];
    float xcv = b2f(xc[tok * 256 + d_stg]);
    g[tok * 256 + d_stg] = f2b((pf + xcv * Dp_stg) * b2f(siluz[tok * 256 + d_stg]));
  }
}

// ---------------- back: m = g@Wmo^T ; rms2+u, gate wsw ; @Wop^T + b + resid (512 thr) ----------------
__global__ __launch_bounds__(512) void back_k(
    const bf16* __restrict__ g, const float* __restrict__ wsf, const void* __restrict__ w2,
    const bf16* __restrict__ u, const bf16* __restrict__ wsw, const void* __restrict__ b_op,
    const void* __restrict__ x, void* __restrict__ out, const int* __restrict__ flagp)
{
  __shared__ __align__(16) short ms[32 * 136];   // aliased as float[32][68] in phase 2
  const int f = *flagp;
  const int tid = threadIdx.x;
  const int tok0 = blockIdx.x * 32;
  const int lane = tid & 63, m = lane & 15, q = lane >> 4;
  const int w = tid >> 6;
  const bf16* WM = (const bf16*)(wsf + OFF_WB) + WB_MO;
  const bf16* WO = (const bf16*)(wsf + OFF_WB) + WB_OP;
  {  // phase 1: m = g@Wmo^T (K=256, N=128); wave w -> nt w
    f32x4 acc[2] = {{0,0,0,0},{0,0,0,0}};
    #pragma unroll
    for (int kk = 0; kk < 8; ++kk) {
      bf16x8 a0 = *(const bf16x8*)(g + (tok0 + m) * 256 + kk * 32 + q * 8);
      bf16x8 a1 = *(const bf16x8*)(g + (tok0 + 16 + m) * 256 + kk * 32 + q * 8);
      int nt = w;
      bf16x8 b = *(const bf16x8*)(WM + (nt * 16 + m) * 256 + kk * 32 + q * 8);
      acc[0] = __builtin_amdgcn_mfma_f32_16x16x32_bf16(a0, b, acc[0], 0, 0, 0);
      acc[1] = __builtin_amdgcn_mfma_f32_16x16x32_bf16(a1, b, acc[1], 0, 0, 0);
    }
    {
      int n = w * 16 + m;
      #pragma unroll
      for (int mt = 0; mt < 2; ++mt)
        #pragma unroll
        for (int r = 0; r < 4; ++r)
          ms[(mt * 16 + q * 4 + r) * 136 + n] = shof(f2b(acc[mt][r]));
    }
  }
  __syncthreads();
  {  // rms2 + u residual + wsw gate (16 threads/token, 8 ch each)
    const int token = tid >> 4, r = tid & 15;
    float mv[8]; float ss = 0.f;
    #pragma unroll
    for (int k = 0; k < 8; ++k) {
      mv[k] = b2f(((const bf16*)ms)[token * 136 + r * 8 + k]);
      ss += mv[k] * mv[k];
    }
    ss += __shfl_xor(ss, 1, 16); ss += __shfl_xor(ss, 2, 16);
    ss += __shfl_xor(ss, 4, 16); ss += __shfl_xor(ss, 8, 16);
    float sc = rsqrtf(ss * (1.f / 128.f) + EPS);
    #pragma unroll
    for (int k = 0; k < 8; ++k) {
      int i = r * 8 + k;
      int ga = (tok0 + token) * 128 + i;
      float v = mv[k] * sc * ldin(w2, i, f) + b2f(u[ga]);
      ms[token * 136 + i] = shof(f2b(v * b2f(wsw[ga])));
    }
  }
  __syncthreads();
  {  // phase 2: out = ms@Wop^T + b_op + resid (K=128, N=64); wave w -> (mt = w>>2, nt = w&3)
    const int mt = w >> 2, nt = w & 3;
    bf16x8 a[4];
    #pragma unroll
    for (int kk = 0; kk < 4; ++kk)
      a[kk] = *(const bf16x8*)&ms[(mt * 16 + m) * 136 + kk * 32 + q * 8];
    __syncthreads();   // all ms reads done; outl alias becomes safe
    f32x4 acc = {0,0,0,0};
    #pragma unroll
    for (int kk = 0; kk < 4; ++kk) {
      bf16x8 b = *(const bf16x8*)(WO + (nt * 16 + m) * 128 + kk * 32 + q * 8);
      acc = __builtin_amdgcn_mfma_f32_16x16x32_bf16(a[kk], b, acc, 0, 0, 0);
    }
    float* outl = (float*)ms;   // [32][68]
    int n = nt * 16 + m;
    #pragma unroll
    for (int r = 0; r < 4; ++r)
      outl[(mt * 16 + q * 4 + r) * 68 + n] = acc[r];
  }
  __syncthreads();
  {  // coalesced copy-out with bias + residual
    const float* outl = (const float*)ms;
    int row = tid >> 4, c0 = (tid & 15) * 4;
    float v[4];
    #pragma unroll
    for (int j = 0; j < 4; ++j)
      v[j] = outl[row * 68 + c0 + j] + ldin(b_op, c0 + j, f)
           + ldin(x, (tok0 + row) * 64 + c0 + j, f);
    if (f) {
      *(float4*)((float*)out + (tok0 + row) * 64 + c0) = make_float4(v[0], v[1], v[2], v[3]);
    } else {
      uint2 pv = make_uint2(pack2(v[0], v[1]), pack2(v[2], v[3]));
      *(uint2*)((bf16*)out + (tok0 + row) * 64 + c0) = pv;
    }
  }
}

// ---------------- launch ----------------
extern "C" void kernel_launch(void* const* d_in, const int* in_sizes, int n_in,
                              void* d_out, int out_size, void* d_ws, size_t ws_size,
                              hipStream_t stream) {
  (void)in_sizes; (void)n_in; (void)out_size; (void)ws_size;
  const void* x        = d_in[0];
  const void* w_norm1  = d_in[1];
  const void* w_norm2  = d_in[2];
  const void* W_ip     = d_in[3];
  const void* b_ip     = d_in[4];
  const void* W_fp     = d_in[5];
  const void* b_fp     = d_in[6];
  const void* W_wp     = d_in[7];
  const void* b_wp     = d_in[8];
  const void* W_op     = d_in[9];
  const void* b_op     = d_in[10];
  const void* in_proj  = d_in[11];
  const void* conv_w   = d_in[12];
  const void* conv_b   = d_in[13];
  const void* x_proj   = d_in[14];
  const void* dt_projw = d_in[15];
  const void* dt_projb = d_in[16];
  const void* A_log    = d_in[17];
  const void* D_par    = d_in[18];
  const void* mo_w     = d_in[19];

  float* wsf    = (float*)d_ws;
  float* xdbl   = wsf + OFF_XDBL;
  bf16*  wsw_b  = (bf16*)(wsf + OFF_WSW);
  bf16*  u_b    = (bf16*)(wsf + OFF_U);
  bf16*  xpre_b = (bf16*)(wsf + OFF_R2);
  float* summ   = wsf + OFF_SUMM;
  float* hin    = wsf + OFF_HIN;
  float* plocp  = wsf + OFF_PLOC;
  float* cumdp  = wsf + OFF_CUMD;
  bf16*  siluz_b= (bf16*)(wsf + OFF_SILUZ);
  bf16*  xc_b   = (bf16*)(wsf + OFF_XC);
  bf16*  g_b    = (bf16*)(wsf + OFF_G);
  int*   flagp  = (int*)(wsf + OFF_FLAG);

  prep_k<<<dim3(592), dim3(256), 0, stream>>>(W_ip, W_wp, W_fp, in_proj, mo_w, W_op,
                                              x_proj, dt_projw, x, wsf, flagp);
  fm_k<<<dim3(NTOK / 32), dim3(512), 0, stream>>>(x, w_norm1, wsf, b_ip, b_wp, b_fp,
                                                  wsw_b, u_b, xpre_b, siluz_b, flagp);
  conv_k<<<dim3(NTOK / 32), dim3(256), 0, stream>>>(xpre_b, conv_w, conv_b, wsf, xc_b, xdbl, flagp);
  scanF_k<<<dim3(16, NCHUNK), dim3(256), 0, stream>>>(xdbl, xc_b, A_log, dt_projb,
                                                      wsf + OFF_WDT, summ, plocp, cumdp, flagp);
  scanB_k<<<dim3(64), dim3(256), 0, stream>>>(summ, hin);
  scanC_k<<<dim3(16, NCHUNK), dim3(256), 0, stream>>>(xdbl, xc_b, siluz_b, A_log, D_par,
                                                      hin, plocp, cumdp, g_b, flagp);
  back_k<<<dim3(NTOK / 32), dim3(512), 0, stream>>>(g_b, wsf, w_norm2, u_b, wsw_b, b_op, x, d_out, flagp);
}

// Round 10
// 188.418 us; speedup vs baseline: 1.0530x; 1.0530x over previous
//
#include <hip/hip_runtime.h>
#include <hip/hip_bf16.h>

typedef __hip_bfloat16 bf16;
typedef __attribute__((ext_vector_type(8))) short bf16x8;
typedef __attribute__((ext_vector_type(4))) float f32x4;
#define DEV __device__ __forceinline__

constexpr int SEQ  = 4096;
constexpr int NB   = 4;
constexpr int NTOK = NB * SEQ;          // 16384 tokens
constexpr float EPS = 1e-5f;
constexpr int NCH = 32;                 // scan chunk length
constexpr int NCHUNK = SEQ / NCH;       // 128 chunks/seq
constexpr float LOG2E = 1.44269504f;

// ---------------- workspace layout (float offsets) ----------------
constexpr int OFF_WDT  = 0;                    // f32 [8][256] dt_proj^T
constexpr int OFF_WB   = 2048;                 // bf16 weight area (151552 shorts)
constexpr int WB_IP = 0;                       // [128][64]
constexpr int WB_WP = 8192;                    // [128][64]
constexpr int WB_FP = 16384;                   // [128][128]
constexpr int WB_PR = 32768;                   // [512][128]
constexpr int WB_MO = 98304;                   // [128][256]
constexpr int WB_OP = 131072;                  // [64][128]
constexpr int WB_XP = 139264;                  // [48][256] (40 real + 8 zero rows)
constexpr int WB_TOT = 151552;
constexpr int OFF_XDBL = OFF_WB + WB_TOT / 2;        // f32 [NTOK][40]
constexpr int OFF_R1   = OFF_XDBL + NTOK * 40;       // (unused)
constexpr int OFF_WSW  = OFF_R1   + 1048576;         // bf16 NTOK*128
constexpr int OFF_U    = OFF_WSW  + 1048576;         // bf16 NTOK*128
constexpr int OFF_R2   = OFF_U    + 1048576;         // xpre
constexpr int OFF_SILUZ= OFF_R2   + 2097152;         // bf16 NTOK*256
constexpr int OFF_XC   = OFF_SILUZ+ 2097152;         // bf16 NTOK*256
constexpr int OFF_G    = OFF_XC   + 2097152;         // (unused since R10)
constexpr int OFF_FLAG = OFF_G    + 2097152;         // int dtype flag
constexpr int OFF_SUMM = OFF_FLAG + 16;              // f32 [64][NCHUNK][256][2]
constexpr int OFF_HIN  = OFF_SUMM + 64 * NCHUNK * 256 * 2;  // f32 [64][NCHUNK][256]
constexpr int OFF_PLOC = OFF_HIN  + 64 * NCHUNK * 256;      // f32 [NTOK][256]
constexpr int OFF_CUMD = OFF_PLOC + NTOK * 256;             // f32 [NTOK][256]

DEV float b2f(bf16 x) { return __bfloat162float(x); }
DEV bf16 f2b(float x) { return __float2bfloat16(x); }
DEV short shof(bf16 h) { short s; __builtin_memcpy(&s, &h, 2); return s; }
DEV float ldin(const void* p, int i, int f) {
  return f ? ((const float*)p)[i] : b2f(((const bf16*)p)[i]);
}
DEV unsigned pack2(float a, float b) {
  bf16 ha = f2b(a), hb = f2b(b);
  unsigned short ua, ub;
  __builtin_memcpy(&ua, &ha, 2); __builtin_memcpy(&ub, &hb, 2);
  return (unsigned)ua | ((unsigned)ub << 16);
}
DEV float lo16f(unsigned u) { return __int_as_float((int)(u << 16)); }
DEV float hi16f(unsigned u) { return __int_as_float((int)(u & 0xffff0000u)); }
template<int CTRL>
DEV float dpp_add(float v) {
  int r = __builtin_amdgcn_update_dpp(0, __float_as_int(v), CTRL, 0xF, 0xF, false);
  return v + __int_as_float(r);
}
DEV float exp2f_fast(float a) { return __builtin_amdgcn_exp2f(a); }
DEV float softplus(float a) {
  return (a > 20.f) ? a : __logf(1.f + exp2f_fast(a * LOG2E));
}
DEV float silu(float a) { return a / (1.f + __expf(-a)); }

// ---------------- prep: inline dtype detect + bf16 weight copies + WDT f32 ----------------
DEV void cpw(int e, int base, int count, const void* __restrict__ src,
             bf16* __restrict__ wb, int f) {
  int r = e - base;
  if (r >= 0 && r < count) wb[base + r] = f2b(ldin(src, r, f));
}
__global__ __launch_bounds__(256) void prep_k(
    const void* __restrict__ w_ip, const void* __restrict__ w_wp, const void* __restrict__ w_fp,
    const void* __restrict__ w_pr, const void* __restrict__ w_mo, const void* __restrict__ w_op,
    const void* __restrict__ w_x,  const void* __restrict__ w_dt,
    const void* __restrict__ x, float* __restrict__ wsf, int* __restrict__ flagp)
{
  __shared__ int cnt;
  if (threadIdx.x == 0) cnt = 0;
  __syncthreads();
  {
    float v = b2f(((const bf16*)x)[threadIdx.x]);
    int ok = (v == v) && fabsf(v) > 1e-4f && fabsf(v) < 100.f;
    atomicAdd(&cnt, ok);
  }
  __syncthreads();
  int f = (cnt > 204) ? 0 : 1;
  if (blockIdx.x == 0 && threadIdx.x == 0) *flagp = f;

  int e = blockIdx.x * 256 + threadIdx.x;   // 592*256 covers 151552
  bf16* wb = (bf16*)(wsf + OFF_WB);
  cpw(e, WB_IP, 8192,  w_ip, wb, f);
  cpw(e, WB_WP, 8192,  w_wp, wb, f);
  cpw(e, WB_FP, 16384, w_fp, wb, f);
  cpw(e, WB_PR, 65536, w_pr, wb, f);
  cpw(e, WB_MO, 32768, w_mo, wb, f);
  cpw(e, WB_OP, 8192,  w_op, wb, f);
  {
    int r = e - WB_XP;
    if (r >= 0 && r < 12288) wb[WB_XP + r] = (r < 10240) ? f2b(ldin(w_x, r, f)) : f2b(0.f);
  }
  if (e < 2048) {
    int r = e >> 8, d = e & 255;
    wsf[OFF_WDT + e] = ldin(w_dt, d * 8 + r, f);
  }
}

// ---------------- fm: rms1 + ip/wp GEMMs + fp GEMM + in_proj GEMM (512 thr / 8 waves) ----------------
__global__ __launch_bounds__(512) void fm_k(
    const void* __restrict__ x, const void* __restrict__ w1, const float* __restrict__ wsf,
    const void* __restrict__ b_ip, const void* __restrict__ b_wp, const void* __restrict__ b_fp,
    bf16* __restrict__ wsw, bf16* __restrict__ u, bf16* __restrict__ xpre,
    bf16* __restrict__ siluz, const int* __restrict__ flagp)
{
  // phase A: xn [0,4608) t1 [4608,13312) ul [13312,22016) wswl [22016,30208)
  // phase B (after GEMM3 frag loads + barrier): xzl [0,33280) aliases all of phase A
  __shared__ __align__(16) char smem[33280];
  short* xn   = (short*)smem;             // [32][72]
  short* t1   = (short*)(smem + 4608);    // [32][136]
  short* ul   = (short*)(smem + 13312);   // [32][136]
  short* wswl = (short*)(smem + 22016);   // [32][128]
  short* xzl  = (short*)smem;             // [32][520] (512 + 8 pad)

  const int f = *flagp;
  const int tid = threadIdx.x;
  const int tok0 = blockIdx.x * 32;
  {  // rms1: 16 threads/token, 4 ch each
    const int token = tid >> 4, r = tid & 15;
    float v[4]; float ss = 0.f;
    #pragma unroll
    for (int k = 0; k < 4; ++k) {
      v[k] = ldin(x, (tok0 + token) * 64 + r * 4 + k, f);
      ss += v[k] * v[k];
    }
    ss += __shfl_xor(ss, 1, 16); ss += __shfl_xor(ss, 2, 16);
    ss += __shfl_xor(ss, 4, 16); ss += __shfl_xor(ss, 8, 16);
    float sc = rsqrtf(ss * (1.f / 64.f) + EPS);
    unsigned* dst = (unsigned*)xn + token * 36 + r * 2;
    #pragma unroll
    for (int k = 0; k < 2; ++k) {
      int i = r * 4 + k * 2;
      dst[k] = pack2(v[k*2] * sc * ldin(w1, i, f), v[k*2+1] * sc * ldin(w1, i + 1, f));
    }
  }
  __syncthreads();
  const int lane = tid & 63, m = lane & 15, q = lane >> 4;
  const int w = tid >> 6;
  {  // GEMM1/1b: K=64, N=128 each. waves 0-3 -> Wip (t1), 4-7 -> Wwp (wswl); 2 nt each
    const int wt = w >> 2, ng = w & 3;
    const bf16* W = (const bf16*)(wsf + OFF_WB) + (wt ? WB_WP : WB_IP);
    const void* bia = wt ? b_wp : b_ip;
    bf16x8 a[2][2];
    #pragma unroll
    for (int mt = 0; mt < 2; ++mt)
      #pragma unroll
      for (int kk = 0; kk < 2; ++kk)
        a[mt][kk] = *(const bf16x8*)&xn[(mt * 16 + m) * 72 + kk * 32 + q * 8];
    #pragma unroll
    for (int nti = 0; nti < 2; ++nti) {
      int nt = ng * 2 + nti;
      int n = nt * 16 + m;
      f32x4 acc[2] = {{0,0,0,0},{0,0,0,0}};
      #pragma unroll
      for (int kk = 0; kk < 2; ++kk) {
        bf16x8 b = *(const bf16x8*)(W + (nt * 16 + m) * 64 + kk * 32 + q * 8);
        #pragma unroll
        for (int mt = 0; mt < 2; ++mt)
          acc[mt] = __builtin_amdgcn_mfma_f32_16x16x32_bf16(a[mt][kk], b, acc[mt], 0, 0, 0);
      }
      float bv = ldin(bia, n, f);
      #pragma unroll
      for (int mt = 0; mt < 2; ++mt)
        #pragma unroll
        for (int r = 0; r < 4; ++r) {
          float v = acc[mt][r] + bv;
          int row = mt * 16 + q * 4 + r;
          if (wt) wswl[row * 128 + n] = shof(f2b(silu(v)));
          else    t1[row * 136 + n] = shof(f2b(v));
        }
    }
  }
  __syncthreads();
  {  // wsw coalesced copy-out
    int row = tid >> 4, c8 = (tid & 15) * 8;
    uint4 v = *(const uint4*)&wswl[row * 128 + c8];
    *(uint4*)(wsw + (tok0 + row) * 128 + c8) = v;
  }
  {  // GEMM2: u = t1@Wfp^T + b_fp. K=128, N=128; wave w -> nt w (LDS only)
    const bf16* WF = (const bf16*)(wsf + OFF_WB) + WB_FP;
    bf16x8 a[2][4];
    #pragma unroll
    for (int mt = 0; mt < 2; ++mt)
      #pragma unroll
      for (int kk = 0; kk < 4; ++kk)
        a[mt][kk] = *(const bf16x8*)&t1[(mt * 16 + m) * 136 + kk * 32 + q * 8];
    {
      int nt = w;
      int n = nt * 16 + m;
      f32x4 acc[2] = {{0,0,0,0},{0,0,0,0}};
      #pragma unroll
      for (int kk = 0; kk < 4; ++kk) {
        bf16x8 b = *(const bf16x8*)(WF + (nt * 16 + m) * 128 + kk * 32 + q * 8);
        #pragma unroll
        for (int mt = 0; mt < 2; ++mt)
          acc[mt] = __builtin_amdgcn_mfma_f32_16x16x32_bf16(a[mt][kk], b, acc[mt], 0, 0, 0);
      }
      float bv = ldin(b_fp, n, f);
      #pragma unroll
      for (int mt = 0; mt < 2; ++mt)
        #pragma unroll
        for (int r = 0; r < 4; ++r)
          ul[(mt * 16 + q * 4 + r) * 136 + n] = shof(f2b(acc[mt][r] + bv));
    }
  }
  __syncthreads();
  {  // u coalesced copy-out
    int row = tid >> 4, c8 = (tid & 15) * 8;
    uint4 v = *(const uint4*)&ul[row * 136 + c8];
    *(uint4*)(u + (tok0 + row) * 128 + c8) = v;
  }
  {  // GEMM3: xz = u@Wpr^T. K=128, N=512; wave w -> nt [4w, 4w+4); results -> xzl
    const bf16* WP = (const bf16*)(wsf + OFF_WB) + WB_PR;
    bf16x8 a[2][4];
    #pragma unroll
    for (int mt = 0; mt < 2; ++mt)
      #pragma unroll
      for (int kk = 0; kk < 4; ++kk)
        a[mt][kk] = *(const bf16x8*)&ul[(mt * 16 + m) * 136 + kk * 32 + q * 8];
    __syncthreads();   // all ul/t1/xn reads done; xzl alias becomes safe
    #pragma unroll
    for (int nti = 0; nti < 4; ++nti) {
      int nt = w * 4 + nti;
      int n = nt * 16 + m;
      f32x4 acc[2] = {{0,0,0,0},{0,0,0,0}};
      #pragma unroll
      for (int kk = 0; kk < 4; ++kk) {
        bf16x8 b = *(const bf16x8*)(WP + (nt * 16 + m) * 128 + kk * 32 + q * 8);
        #pragma unroll
        for (int mt = 0; mt < 2; ++mt)
          acc[mt] = __builtin_amdgcn_mfma_f32_16x16x32_bf16(a[mt][kk], b, acc[mt], 0, 0, 0);
      }
      #pragma unroll
      for (int mt = 0; mt < 2; ++mt)
        #pragma unroll
        for (int r = 0; r < 4; ++r) {
          int row = mt * 16 + q * 4 + r;
          float v = acc[mt][r];
          xzl[row * 520 + n] = shof(f2b(n < 256 ? v : silu(v)));
        }
    }
  }
  __syncthreads();
  {  // xz coalesced copy-out
    #pragma unroll
    for (int k = 0; k < 4; ++k) {
      int chunk = tid + k * 512;
      int row = chunk >> 6, seg = chunk & 63;
      uint4 v = *(const uint4*)&xzl[row * 520 + seg * 8];
      int n0 = seg * 8;
      if (n0 < 256) *(uint4*)(xpre + (tok0 + row) * 256 + n0) = v;
      else          *(uint4*)(siluz + (tok0 + row) * 256 + (n0 - 256)) = v;
    }
  }
}

// ---------------- conv (depthwise w4 + silu) + x_proj MFMA -> xc, xdbl ----------------
__global__ __launch_bounds__(256) void conv_k(
    const bf16* __restrict__ xpre, const void* __restrict__ cw, const void* __restrict__ cb,
    const float* __restrict__ wsf, bf16* __restrict__ xc, float* __restrict__ xdbl,
    const int* __restrict__ flagp)
{
  __shared__ short xh[35 * 256];
  __shared__ short cs[32 * 264];
  const int f = *flagp;
  const int tid = threadIdx.x;
  const int tok0 = blockIdx.x * 32;
  const bool seqstart = (tok0 & (SEQ - 1)) == 0;
  for (int c = tid; c < 1120; c += 256) {
    int e0 = c * 8;
    int tt = e0 >> 8, i = e0 & 255;
    int gtok = tok0 + tt - 3;
    uint4* dst = (uint4*)(xh + e0);
    if (gtok >= 0 && !(seqstart && tt < 3)) *dst = *(const uint4*)(xpre + gtok * 256 + i);
    else                                    *dst = make_uint4(0, 0, 0, 0);
  }
  __syncthreads();
  {
    const int ch0 = (tid & 63) * 4;
    const int t0 = (tid >> 6) * 8;
    float w4[4][4], cb4[4];
    #pragma unroll
    for (int c = 0; c < 4; ++c) {
      cb4[c] = ldin(cb, ch0 + c, f);
      #pragma unroll
      for (int k = 0; k < 4; ++k) w4[c][k] = ldin(cw, (ch0 + c) * 4 + k, f);
    }
    float win[11][4];
    #pragma unroll
    for (int r = 0; r < 11; ++r) {
      uint2 v = *(const uint2*)&xh[(t0 + r) * 256 + ch0];
      win[r][0] = lo16f(v.x); win[r][1] = hi16f(v.x);
      win[r][2] = lo16f(v.y); win[r][3] = hi16f(v.y);
    }
    #pragma unroll
    for (int t = 0; t < 8; ++t) {
      unsigned pk[2];
      #pragma unroll
      for (int cp = 0; cp < 2; ++cp) {
        float o[2];
        #pragma unroll
        for (int ci = 0; ci < 2; ++ci) {
          int c = cp * 2 + ci;
          float acc = cb4[c];
          #pragma unroll
          for (int k = 0; k < 4; ++k) acc = fmaf(win[t + k][c], w4[c][k], acc);
          o[ci] = silu(acc);
        }
        pk[cp] = pack2(o[0], o[1]);
      }
      uint2 pv = make_uint2(pk[0], pk[1]);
      *(uint2*)&cs[(t0 + t) * 264 + ch0] = pv;
      *(uint2*)(xc + (tok0 + t0 + t) * 256 + ch0) = pv;
    }
  }
  __syncthreads();
  const int w = tid >> 6;
  if (w < 2) {
    const bf16* Wx = (const bf16*)(wsf + OFF_WB) + WB_XP;
    const int lane = tid & 63, m = lane & 15, quad = lane >> 4;
    f32x4 acc[3] = {{0,0,0,0},{0,0,0,0},{0,0,0,0}};
    #pragma unroll
    for (int k0 = 0; k0 < 256; k0 += 32) {
      bf16x8 af = *(const bf16x8*)&cs[(w * 16 + m) * 264 + k0 + quad * 8];
      #pragma unroll
      for (int nt = 0; nt < 3; ++nt) {
        bf16x8 bfr = *(const bf16x8*)(Wx + (nt * 16 + m) * 256 + k0 + quad * 8);
        acc[nt] = __builtin_amdgcn_mfma_f32_16x16x32_bf16(af, bfr, acc[nt], 0, 0, 0);
      }
    }
    #pragma unroll
    for (int nt = 0; nt < 3; ++nt) {
      int n = nt * 16 + m;
      if (n < 40) {
        #pragma unroll
        for (int r = 0; r < 4; ++r)
          xdbl[(tok0 + w * 16 + quad * 4 + r) * 40 + n] = acc[nt][r];
      }
    }
  }
}

// ---------------- scan pass F: local chunk scan + p_local/cumdlt/summary ----------------
__global__ __launch_bounds__(256) void scanF_k(
    const float* __restrict__ xdbl, const bf16* __restrict__ xc,
    const void* __restrict__ A_log, const void* __restrict__ dt_b,
    const float* __restrict__ WDT, float* __restrict__ summ,
    float* __restrict__ ploc, float* __restrict__ cumd, const int* __restrict__ flagp)
{
  const int f = *flagp;
  const int tid = threadIdx.x;
  const int bb = blockIdx.x >> 2, dgsup = blockIdx.x & 3, c = blockIdx.y;
  const int dgsub = tid >> 6, lane = tid & 63, dl = lane >> 2, squad = lane & 3;
  const int dg = dgsup * 4 + dgsub;
  const int bxOld = bb * 16 + dg;
  const int d_comp = dg * 16 + dl;
  const int bd = tid & 63;
  const int d_stg = dgsup * 64 + bd;
  const int bdc = dgsub * 16 + dl;
  const int tok_base = bb * SEQ + c * NCH;

  __shared__ float dt_l[NCH * 8];     // 1 KB
  __shared__ float dx_l[16 * 64 * 2]; // 8 KB
  __shared__ float Bp[16 * 16];       // 1 KB
  __shared__ float Cp[16 * 16];       // 1 KB
  __shared__ float pg_l[16 * 64];     // 4 KB
  __shared__ float cd_l[16 * 64];     // 4 KB

  float Aval2[4];
  #pragma unroll
  for (int j = 0; j < 4; ++j)
    Aval2[j] = -__expf(ldin(A_log, d_comp * 16 + squad * 4 + j, f)) * LOG2E;
  const float dtb_stg = ldin(dt_b, d_stg, f);
  float wdt[8];
  #pragma unroll
  for (int r = 0; r < 8; ++r) wdt[r] = WDT[r * 256 + d_stg];

  float h[4] = {0.f, 0.f, 0.f, 0.f};
  float sdlt = 0.f;

  if (tid < 64)   // dt_l: whole chunk, [t][8]; 2 threads/token
    *(float4*)(dt_l + tid * 4) = *(const float4*)(xdbl + (tok_base + (tid >> 1)) * 40 + (tid & 1) * 4);

  #pragma unroll 1
  for (int half = 0; half < 2; ++half) {
    const int tb = half * 16;
    __syncthreads();   // prev-half pg/cd reads done; dt_l ready for half 0
    {   // B/C planes: [t-half][s]
      int tl = tid >> 4, s = tid & 15;
      int tok = tok_base + tb + tl;
      Bp[tid] = xdbl[tok * 40 + 8 + s];
      Cp[tid] = xdbl[tok * 40 + 24 + s];
    }
    #pragma unroll
    for (int k = 0; k < 4; ++k) {   // dx: [t-half][bd]
      int tl = (tid >> 6) + k * 4;
      int tok = tok_base + tb + tl;
      const float* dtr = dt_l + (tb + tl) * 8;
      float a = dtb_stg;
      #pragma unroll
      for (int r = 0; r < 8; ++r) a = fmaf(dtr[r], wdt[r], a);
      float dlt = softplus(a);
      float xcv = b2f(xc[tok * 256 + d_stg]);
      *(float2*)(dx_l + (tl * 64 + bd) * 2) = make_float2(dlt, dlt * xcv);
    }
    __syncthreads();

    #pragma unroll 8
    for (int tl = 0; tl < 16; ++tl) {
      float2 dx = *(const float2*)(dx_l + (tl * 64 + bdc) * 2);   // quad-broadcast
      float4 B4 = *(const float4*)(Bp + tl * 16 + squad * 4);
      float Bv[4] = {B4.x, B4.y, B4.z, B4.w};
      #pragma unroll
      for (int j = 0; j < 4; ++j) {
        float dA = exp2f_fast(dx.x * Aval2[j]);
        h[j] = fmaf(dA, h[j], dx.y * Bv[j]);
      }
      sdlt += dx.x;
      float4 C4 = *(const float4*)(Cp + tl * 16 + squad * 4);
      float p = h[0] * C4.x;
      p = fmaf(h[1], C4.y, p);
      p = fmaf(h[2], C4.z, p);
      p = fmaf(h[3], C4.w, p);
      p = dpp_add<0xB1>(p);   // quad xor1
      p = dpp_add<0x4E>(p);   // quad xor2
      if (squad == 0) { pg_l[tl * 64 + bdc] = p; cd_l[tl * 64 + bdc] = sdlt; }
    }
    __syncthreads();
    #pragma unroll
    for (int k = 0; k < 4; ++k) {   // coalesced p_local / cumdlt out
      int tl = (tid >> 6) + k * 4;
      int tok = tok_base + tb + tl;
      ploc[tok * 256 + d_stg] = pg_l[tl * 64 + bd];
      cumd[tok * 256 + d_stg] = cd_l[tl * 64 + bd];
    }
  }

  float* dst = summ + ((bxOld * NCHUNK + c) * 256 + dl * 16 + squad * 4) * 2;
  *(float4*)(dst)     = make_float4(exp2f_fast(Aval2[0] * sdlt), h[0],
                                    exp2f_fast(Aval2[1] * sdlt), h[1]);
  *(float4*)(dst + 4) = make_float4(exp2f_fast(Aval2[2] * sdlt), h[2],
                                    exp2f_fast(Aval2[3] * sdlt), h[3]);
}

// phase B: exclusive scan over chunk summaries, 16-deep load batching
__global__ __launch_bounds__(256) void scanB_k(const float* __restrict__ summ, float* __restrict__ hinit) {
  int bx = blockIdx.x, qq = threadIdx.x;
  float h = 0.f;
  for (int c0 = 0; c0 < NCHUNK; c0 += 16) {
    float2 sv[16];
    #pragma unroll
    for (int k = 0; k < 16; ++k)
      sv[k] = *(const float2*)(summ + ((bx * NCHUNK + c0 + k) * 256 + qq) * 2);
    #pragma unroll
    for (int k = 0; k < 16; ++k) {
      hinit[(bx * NCHUNK + c0 + k) * 256 + qq] = h;
      h = fmaf(sv[k].x, h, sv[k].y);
    }
  }
}

// ---------------- backC: scanC correction (g in LDS) + m GEMM + rms2/gate + out GEMM ----------------
// Fusion valid because scanC chunk (32 tok) == back block (32 tok) and g had a single consumer.
__global__ __launch_bounds__(512) void backC_k(
    const float* __restrict__ xdbl, const bf16* __restrict__ xc, const bf16* __restrict__ siluz,
    const void* __restrict__ A_log, const void* __restrict__ D_par,
    const float* __restrict__ hinit, const float* __restrict__ ploc, const float* __restrict__ cumd,
    const float* __restrict__ wsf, const void* __restrict__ w2,
    const bf16* __restrict__ u, const bf16* __restrict__ wsw, const void* __restrict__ b_op,
    const void* __restrict__ x, void* __restrict__ out, const int* __restrict__ flagp)
{
  // gl [0,16896): bf16 [32][264] (g tile, padded). Cp [16896,18944): f32 [32][16].
  // cdl [18944,35328): f32 [32][128]. gcl [35328,51712): f32 [32][128].
  // ms aliases cdl region after the scan part (barrier-guarded); outl aliases ms.
  __shared__ __align__(16) char smem[51712];
  short* gl  = (short*)smem;
  float* Cp  = (float*)(smem + 16896);
  float* cdl = (float*)(smem + 18944);
  float* gcl = (float*)(smem + 35328);
  short* ms  = (short*)(smem + 18944);

  const int f = *flagp;
  const int tid = threadIdx.x;
  const int tok0 = blockIdx.x * 32;
  const int bb = tok0 >> 12;                  // /SEQ
  const int c  = (tok0 & (SEQ - 1)) >> 5;     // /NCH
  const int w = tid >> 6, lane = tid & 63;
  const int dl = lane >> 2, squad = lane & 3;
  const int chL = w * 16 + dl;                // 0..127 compute channel-within-pass
  const int chE = tid & 127;                  // epilogue/staging channel-within-pass

  {  // stage C plane once: 32 tok x 16 s
    int tl = tid >> 4, s = tid & 15;
    Cp[tid] = xdbl[(tok0 + tl) * 40 + 24 + s];
  }

  #pragma unroll 1
  for (int p = 0; p < 2; ++p) {
    const int ch = p * 128 + chL;
    #pragma unroll
    for (int k = 0; k < 8; ++k) {   // stage cumdlt [tl][chE]
      int tl = (tid >> 7) + k * 4;
      cdl[tl * 128 + chE] = cumd[(tok0 + tl) * 256 + p * 128 + chE];
    }
    float Aval2[4];
    #pragma unroll
    for (int j = 0; j < 4; ++j)
      Aval2[j] = -__expf(ldin(A_log, ch * 16 + squad * 4 + j, f)) * LOG2E;
    float4 hv = *(const float4*)(hinit +
        ((bb * 16 + (ch >> 4)) * NCHUNK + c) * 256 + (ch & 15) * 16 + squad * 4);
    __syncthreads();
    #pragma unroll 8
    for (int tl = 0; tl < 32; ++tl) {
      float cum = cdl[tl * 128 + chL];                 // quad-broadcast
      float4 C4 = *(const float4*)(Cp + tl * 16 + squad * 4);
      float pv =      C4.x * exp2f_fast(cum * Aval2[0]) * hv.x;
      pv = fmaf(C4.y * exp2f_fast(cum * Aval2[1]), hv.y, pv);
      pv = fmaf(C4.z * exp2f_fast(cum * Aval2[2]), hv.z, pv);
      pv = fmaf(C4.w * exp2f_fast(cum * Aval2[3]), hv.w, pv);
      pv = dpp_add<0xB1>(pv);   // quad xor1
      pv = dpp_add<0x4E>(pv);   // quad xor2
      if (squad == 0) gcl[tl * 128 + chL] = pv;
    }
    __syncthreads();
    {  // g epilogue into LDS tile
      const int gch = p * 128 + chE;
      const float Dp = ldin(D_par, gch, f);
      #pragma unroll
      for (int k = 0; k < 8; ++k) {
        int tl = (tid >> 7) + k * 4;
        int tok = tok0 + tl;
        float pf = gcl[tl * 128 + chE] + ploc[tok * 256 + gch];
        float xcv = b2f(xc[tok * 256 + gch]);
        gl[tl * 264 + gch] = shof(f2b((pf + xcv * Dp) * b2f(siluz[tok * 256 + gch])));
      }
    }
    __syncthreads();   // cdl safe to restage (p=1) / alias as ms later
  }

  const int m = lane & 15, q = lane >> 4;
  const bf16* WM = (const bf16*)(wsf + OFF_WB) + WB_MO;
  const bf16* WO = (const bf16*)(wsf + OFF_WB) + WB_OP;
  {  // phase 1: m = g@Wmo^T (K=256, N=128); wave w -> nt w; g from LDS
    f32x4 acc[2] = {{0,0,0,0},{0,0,0,0}};
    #pragma unroll
    for (int kk = 0; kk < 8; ++kk) {
      bf16x8 a0 = *(const bf16x8*)&gl[m * 264 + kk * 32 + q * 8];
      bf16x8 a1 = *(const bf16x8*)&gl[(16 + m) * 264 + kk * 32 + q * 8];
      int nt = w;
      bf16x8 b = *(const bf16x8*)(WM + (nt * 16 + m) * 256 + kk * 32 + q * 8);
      acc[0] = __builtin_amdgcn_mfma_f32_16x16x32_bf16(a0, b, acc[0], 0, 0, 0);
      acc[1] = __builtin_amdgcn_mfma_f32_16x16x32_bf16(a1, b, acc[1], 0, 0, 0);
    }
    {
      int n = w * 16 + m;
      #pragma unroll
      for (int mt = 0; mt < 2; ++mt)
        #pragma unroll
        for (int r = 0; r < 4; ++r)
          ms[(mt * 16 + q * 4 + r) * 136 + n] = shof(f2b(acc[mt][r]));
    }
  }
  __syncthreads();
  {  // rms2 + u residual + wsw gate (16 threads/token, 8 ch each)
    const int token = tid >> 4, r = tid & 15;
    float mv[8]; float ss = 0.f;
    #pragma unroll
    for (int k = 0; k < 8; ++k) {
      mv[k] = b2f(((const bf16*)ms)[token * 136 + r * 8 + k]);
      ss += mv[k] * mv[k];
    }
    ss += __shfl_xor(ss, 1, 16); ss += __shfl_xor(ss, 2, 16);
    ss += __shfl_xor(ss, 4, 16); ss += __shfl_xor(ss, 8, 16);
    float sc = rsqrtf(ss * (1.f / 128.f) + EPS);
    #pragma unroll
    for (int k = 0; k < 8; ++k) {
      int i = r * 8 + k;
      int ga = (tok0 + token) * 128 + i;
      float v = mv[k] * sc * ldin(w2, i, f) + b2f(u[ga]);
      ms[token * 136 + i] = shof(f2b(v * b2f(wsw[ga])));
    }
  }
  __syncthreads();
  {  // phase 2: out = ms@Wop^T + b_op + resid (K=128, N=64); wave w -> (mt = w>>2, nt = w&3)
    const int mt = w >> 2, nt = w & 3;
    bf16x8 a[4];
    #pragma unroll
    for (int kk = 0; kk < 4; ++kk)
      a[kk] = *(const bf16x8*)&ms[(mt * 16 + m) * 136 + kk * 32 + q * 8];
    __syncthreads();   // all ms reads done; outl alias becomes safe
    f32x4 acc = {0,0,0,0};
    #pragma unroll
    for (int kk = 0; kk < 4; ++kk) {
      bf16x8 b = *(const bf16x8*)(WO + (nt * 16 + m) * 128 + kk * 32 + q * 8);
      acc = __builtin_amdgcn_mfma_f32_16x16x32_bf16(a[kk], b, acc, 0, 0, 0);
    }
    float* outl = (float*)ms;   // [32][68]
    int n = nt * 16 + m;
    #pragma unroll
    for (int r = 0; r < 4; ++r)
      outl[(mt * 16 + q * 4 + r) * 68 + n] = acc[r];
  }
  __syncthreads();
  {  // coalesced copy-out with bias + residual
    const float* outl = (const float*)ms;
    int row = tid >> 4, c0 = (tid & 15) * 4;
    float v[4];
    #pragma unroll
    for (int j = 0; j < 4; ++j)
      v[j] = outl[row * 68 + c0 + j] + ldin(b_op, c0 + j, f)
           + ldin(x, (tok0 + row) * 64 + c0 + j, f);
    if (f) {
      *(float4*)((float*)out + (tok0 + row) * 64 + c0) = make_float4(v[0], v[1], v[2], v[3]);
    } else {
      uint2 pv = make_uint2(pack2(v[0], v[1]), pack2(v[2], v[3]));
      *(uint2*)((bf16*)out + (tok0 + row) * 64 + c0) = pv;
    }
  }
}

// ---------------- launch ----------------
extern "C" void kernel_launch(void* const* d_in, const int* in_sizes, int n_in,
                              void* d_out, int out_size, void* d_ws, size_t ws_size,
                              hipStream_t stream) {
  (void)in_sizes; (void)n_in; (void)out_size; (void)ws_size;
  const void* x        = d_in[0];
  const void* w_norm1  = d_in[1];
  const void* w_norm2  = d_in[2];
  const void* W_ip     = d_in[3];
  const void* b_ip     = d_in[4];
  const void* W_fp     = d_in[5];
  const void* b_fp     = d_in[6];
  const void* W_wp     = d_in[7];
  const void* b_wp     = d_in[8];
  const void* W_op     = d_in[9];
  const void* b_op     = d_in[10];
  const void* in_proj  = d_in[11];
  const void* conv_w   = d_in[12];
  const void* conv_b   = d_in[13];
  const void* x_proj   = d_in[14];
  const void* dt_projw = d_in[15];
  const void* dt_projb = d_in[16];
  const void* A_log    = d_in[17];
  const void* D_par    = d_in[18];
  const void* mo_w     = d_in[19];

  float* wsf    = (float*)d_ws;
  float* xdbl   = wsf + OFF_XDBL;
  bf16*  wsw_b  = (bf16*)(wsf + OFF_WSW);
  bf16*  u_b    = (bf16*)(wsf + OFF_U);
  bf16*  xpre_b = (bf16*)(wsf + OFF_R2);
  float* summ   = wsf + OFF_SUMM;
  float* hin    = wsf + OFF_HIN;
  float* plocp  = wsf + OFF_PLOC;
  float* cumdp  = wsf + OFF_CUMD;
  bf16*  siluz_b= (bf16*)(wsf + OFF_SILUZ);
  bf16*  xc_b   = (bf16*)(wsf + OFF_XC);
  int*   flagp  = (int*)(wsf + OFF_FLAG);

  prep_k<<<dim3(592), dim3(256), 0, stream>>>(W_ip, W_wp, W_fp, in_proj, mo_w, W_op,
                                              x_proj, dt_projw, x, wsf, flagp);
  fm_k<<<dim3(NTOK / 32), dim3(512), 0, stream>>>(x, w_norm1, wsf, b_ip, b_wp, b_fp,
                                                  wsw_b, u_b, xpre_b, siluz_b, flagp);
  conv_k<<<dim3(NTOK / 32), dim3(256), 0, stream>>>(xpre_b, conv_w, conv_b, wsf, xc_b, xdbl, flagp);
  scanF_k<<<dim3(16, NCHUNK), dim3(256), 0, stream>>>(xdbl, xc_b, A_log, dt_projb,
                                                      wsf + OFF_WDT, summ, plocp, cumdp, flagp);
  scanB_k<<<dim3(64), dim3(256), 0, stream>>>(summ, hin);
  backC_k<<<dim3(NTOK / 32), dim3(512), 0, stream>>>(xdbl, xc_b, siluz_b, A_log, D_par,
                                                     hin, plocp, cumdp, wsf, w_norm2,
                                                     u_b, wsw_b, b_op, x, d_out, flagp);
}

// Round 11
// 186.844 us; speedup vs baseline: 1.0619x; 1.0084x over previous
//
#include <hip/hip_runtime.h>
#include <hip/hip_bf16.h>

typedef __hip_bfloat16 bf16;
typedef __attribute__((ext_vector_type(8))) short bf16x8;
typedef __attribute__((ext_vector_type(4))) float f32x4;
#define DEV __device__ __forceinline__

constexpr int SEQ  = 4096;
constexpr int NB   = 4;
constexpr int NTOK = NB * SEQ;          // 16384 tokens
constexpr float EPS = 1e-5f;
constexpr int NCH = 32;                 // scan chunk length
constexpr int NCHUNK = SEQ / NCH;       // 128 chunks/seq
constexpr float LOG2E = 1.44269504f;

// ---------------- workspace layout (float offsets) ----------------
constexpr int OFF_WDT  = 0;                    // f32 [8][256] dt_proj^T
constexpr int OFF_WB   = 2048;                 // bf16 weight area (151552 shorts)
constexpr int WB_IP = 0;                       // [128][64]
constexpr int WB_WP = 8192;                    // [128][64]
constexpr int WB_FP = 16384;                   // [128][128]
constexpr int WB_PR = 32768;                   // [512][128]
constexpr int WB_MO = 98304;                   // [128][256]
constexpr int WB_OP = 131072;                  // [64][128]
constexpr int WB_XP = 139264;                  // [48][256] (40 real + 8 zero rows)
constexpr int WB_TOT = 151552;
constexpr int OFF_XDBL = OFF_WB + WB_TOT / 2;        // f32 [NTOK][40]
constexpr int OFF_R1   = OFF_XDBL + NTOK * 40;       // (unused)
constexpr int OFF_WSW  = OFF_R1   + 1048576;         // bf16 NTOK*128
constexpr int OFF_U    = OFF_WSW  + 1048576;         // bf16 NTOK*128
constexpr int OFF_R2   = OFF_U    + 1048576;         // xpre
constexpr int OFF_SILUZ= OFF_R2   + 2097152;         // bf16 NTOK*256
constexpr int OFF_XC   = OFF_SILUZ+ 2097152;         // bf16 NTOK*256
constexpr int OFF_G    = OFF_XC   + 2097152;         // (unused)
constexpr int OFF_FLAG = OFF_G    + 2097152;         // int dtype flag
constexpr int OFF_SUMM = OFF_FLAG + 16;              // f32 [64][NCHUNK][256][2]
constexpr int OFF_HIN  = OFF_SUMM + 64 * NCHUNK * 256 * 2;  // f32 [64][NCHUNK][256]

DEV float b2f(bf16 x) { return __bfloat162float(x); }
DEV bf16 f2b(float x) { return __float2bfloat16(x); }
DEV short shof(bf16 h) { short s; __builtin_memcpy(&s, &h, 2); return s; }
DEV float ldin(const void* p, int i, int f) {
  return f ? ((const float*)p)[i] : b2f(((const bf16*)p)[i]);
}
DEV unsigned pack2(float a, float b) {
  bf16 ha = f2b(a), hb = f2b(b);
  unsigned short ua, ub;
  __builtin_memcpy(&ua, &ha, 2); __builtin_memcpy(&ub, &hb, 2);
  return (unsigned)ua | ((unsigned)ub << 16);
}
DEV float lo16f(unsigned u) { return __int_as_float((int)(u << 16)); }
DEV float hi16f(unsigned u) { return __int_as_float((int)(u & 0xffff0000u)); }
template<int CTRL>
DEV float dpp_add(float v) {
  int r = __builtin_amdgcn_update_dpp(0, __float_as_int(v), CTRL, 0xF, 0xF, false);
  return v + __int_as_float(r);
}
DEV float exp2f_fast(float a) { return __builtin_amdgcn_exp2f(a); }
DEV float softplus(float a) {
  return (a > 20.f) ? a : __logf(1.f + exp2f_fast(a * LOG2E));
}
DEV float silu(float a) { return a / (1.f + __expf(-a)); }

// ---------------- prep: inline dtype detect + bf16 weight copies + WDT f32 ----------------
DEV void cpw(int e, int base, int count, const void* __restrict__ src,
             bf16* __restrict__ wb, int f) {
  int r = e - base;
  if (r >= 0 && r < count) wb[base + r] = f2b(ldin(src, r, f));
}
__global__ __launch_bounds__(256) void prep_k(
    const void* __restrict__ w_ip, const void* __restrict__ w_wp, const void* __restrict__ w_fp,
    const void* __restrict__ w_pr, const void* __restrict__ w_mo, const void* __restrict__ w_op,
    const void* __restrict__ w_x,  const void* __restrict__ w_dt,
    const void* __restrict__ x, float* __restrict__ wsf, int* __restrict__ flagp)
{
  __shared__ int cnt;
  if (threadIdx.x == 0) cnt = 0;
  __syncthreads();
  {
    float v = b2f(((const bf16*)x)[threadIdx.x]);
    int ok = (v == v) && fabsf(v) > 1e-4f && fabsf(v) < 100.f;
    atomicAdd(&cnt, ok);
  }
  __syncthreads();
  int f = (cnt > 204) ? 0 : 1;
  if (blockIdx.x == 0 && threadIdx.x == 0) *flagp = f;

  int e = blockIdx.x * 256 + threadIdx.x;   // 592*256 covers 151552
  bf16* wb = (bf16*)(wsf + OFF_WB);
  cpw(e, WB_IP, 8192,  w_ip, wb, f);
  cpw(e, WB_WP, 8192,  w_wp, wb, f);
  cpw(e, WB_FP, 16384, w_fp, wb, f);
  cpw(e, WB_PR, 65536, w_pr, wb, f);
  cpw(e, WB_MO, 32768, w_mo, wb, f);
  cpw(e, WB_OP, 8192,  w_op, wb, f);
  {
    int r = e - WB_XP;
    if (r >= 0 && r < 12288) wb[WB_XP + r] = (r < 10240) ? f2b(ldin(w_x, r, f)) : f2b(0.f);
  }
  if (e < 2048) {
    int r = e >> 8, d = e & 255;
    wsf[OFF_WDT + e] = ldin(w_dt, d * 8 + r, f);
  }
}

// ---------------- fm: rms1 + ip/wp GEMMs + fp GEMM + in_proj GEMM (512 thr / 8 waves) ----------------
__global__ __launch_bounds__(512) void fm_k(
    const void* __restrict__ x, const void* __restrict__ w1, const float* __restrict__ wsf,
    const void* __restrict__ b_ip, const void* __restrict__ b_wp, const void* __restrict__ b_fp,
    bf16* __restrict__ wsw, bf16* __restrict__ u, bf16* __restrict__ xpre,
    bf16* __restrict__ siluz, const int* __restrict__ flagp)
{
  // phase A: xn [0,4608) t1 [4608,13312) ul [13312,22016) wswl [22016,30208)
  // phase B (after GEMM3 frag loads + barrier): xzl [0,33280) aliases all of phase A
  __shared__ __align__(16) char smem[33280];
  short* xn   = (short*)smem;             // [32][72]
  short* t1   = (short*)(smem + 4608);    // [32][136]
  short* ul   = (short*)(smem + 13312);   // [32][136]
  short* wswl = (short*)(smem + 22016);   // [32][128]
  short* xzl  = (short*)smem;             // [32][520] (512 + 8 pad)

  const int f = *flagp;
  const int tid = threadIdx.x;
  const int tok0 = blockIdx.x * 32;
  {  // rms1: 16 threads/token, 4 ch each
    const int token = tid >> 4, r = tid & 15;
    float v[4]; float ss = 0.f;
    #pragma unroll
    for (int k = 0; k < 4; ++k) {
      v[k] = ldin(x, (tok0 + token) * 64 + r * 4 + k, f);
      ss += v[k] * v[k];
    }
    ss += __shfl_xor(ss, 1, 16); ss += __shfl_xor(ss, 2, 16);
    ss += __shfl_xor(ss, 4, 16); ss += __shfl_xor(ss, 8, 16);
    float sc = rsqrtf(ss * (1.f / 64.f) + EPS);
    unsigned* dst = (unsigned*)xn + token * 36 + r * 2;
    #pragma unroll
    for (int k = 0; k < 2; ++k) {
      int i = r * 4 + k * 2;
      dst[k] = pack2(v[k*2] * sc * ldin(w1, i, f), v[k*2+1] * sc * ldin(w1, i + 1, f));
    }
  }
  __syncthreads();
  const int lane = tid & 63, m = lane & 15, q = lane >> 4;
  const int w = tid >> 6;
  {  // GEMM1/1b: K=64, N=128 each. waves 0-3 -> Wip (t1), 4-7 -> Wwp (wswl); 2 nt each
    const int wt = w >> 2, ng = w & 3;
    const bf16* W = (const bf16*)(wsf + OFF_WB) + (wt ? WB_WP : WB_IP);
    const void* bia = wt ? b_wp : b_ip;
    bf16x8 a[2][2];
    #pragma unroll
    for (int mt = 0; mt < 2; ++mt)
      #pragma unroll
      for (int kk = 0; kk < 2; ++kk)
        a[mt][kk] = *(const bf16x8*)&xn[(mt * 16 + m) * 72 + kk * 32 + q * 8];
    #pragma unroll
    for (int nti = 0; nti < 2; ++nti) {
      int nt = ng * 2 + nti;
      int n = nt * 16 + m;
      f32x4 acc[2] = {{0,0,0,0},{0,0,0,0}};
      #pragma unroll
      for (int kk = 0; kk < 2; ++kk) {
        bf16x8 b = *(const bf16x8*)(W + (nt * 16 + m) * 64 + kk * 32 + q * 8);
        #pragma unroll
        for (int mt = 0; mt < 2; ++mt)
          acc[mt] = __builtin_amdgcn_mfma_f32_16x16x32_bf16(a[mt][kk], b, acc[mt], 0, 0, 0);
      }
      float bv = ldin(bia, n, f);
      #pragma unroll
      for (int mt = 0; mt < 2; ++mt)
        #pragma unroll
        for (int r = 0; r < 4; ++r) {
          float v = acc[mt][r] + bv;
          int row = mt * 16 + q * 4 + r;
          if (wt) wswl[row * 128 + n] = shof(f2b(silu(v)));
          else    t1[row * 136 + n] = shof(f2b(v));
        }
    }
  }
  __syncthreads();
  {  // wsw coalesced copy-out
    int row = tid >> 4, c8 = (tid & 15) * 8;
    uint4 v = *(const uint4*)&wswl[row * 128 + c8];
    *(uint4*)(wsw + (tok0 + row) * 128 + c8) = v;
  }
  {  // GEMM2: u = t1@Wfp^T + b_fp. K=128, N=128; wave w -> nt w (LDS only)
    const bf16* WF = (const bf16*)(wsf + OFF_WB) + WB_FP;
    bf16x8 a[2][4];
    #pragma unroll
    for (int mt = 0; mt < 2; ++mt)
      #pragma unroll
      for (int kk = 0; kk < 4; ++kk)
        a[mt][kk] = *(const bf16x8*)&t1[(mt * 16 + m) * 136 + kk * 32 + q * 8];
    {
      int nt = w;
      int n = nt * 16 + m;
      f32x4 acc[2] = {{0,0,0,0},{0,0,0,0}};
      #pragma unroll
      for (int kk = 0; kk < 4; ++kk) {
        bf16x8 b = *(const bf16x8*)(WF + (nt * 16 + m) * 128 + kk * 32 + q * 8);
        #pragma unroll
        for (int mt = 0; mt < 2; ++mt)
          acc[mt] = __builtin_amdgcn_mfma_f32_16x16x32_bf16(a[mt][kk], b, acc[mt], 0, 0, 0);
      }
      float bv = ldin(b_fp, n, f);
      #pragma unroll
      for (int mt = 0; mt < 2; ++mt)
        #pragma unroll
        for (int r = 0; r < 4; ++r)
          ul[(mt * 16 + q * 4 + r) * 136 + n] = shof(f2b(acc[mt][r] + bv));
    }
  }
  __syncthreads();
  {  // u coalesced copy-out
    int row = tid >> 4, c8 = (tid & 15) * 8;
    uint4 v = *(const uint4*)&ul[row * 136 + c8];
    *(uint4*)(u + (tok0 + row) * 128 + c8) = v;
  }
  {  // GEMM3: xz = u@Wpr^T. K=128, N=512; wave w -> nt [4w, 4w+4); results -> xzl
    const bf16* WP = (const bf16*)(wsf + OFF_WB) + WB_PR;
    bf16x8 a[2][4];
    #pragma unroll
    for (int mt = 0; mt < 2; ++mt)
      #pragma unroll
      for (int kk = 0; kk < 4; ++kk)
        a[mt][kk] = *(const bf16x8*)&ul[(mt * 16 + m) * 136 + kk * 32 + q * 8];
    __syncthreads();   // all ul/t1/xn reads done; xzl alias becomes safe
    #pragma unroll
    for (int nti = 0; nti < 4; ++nti) {
      int nt = w * 4 + nti;
      int n = nt * 16 + m;
      f32x4 acc[2] = {{0,0,0,0},{0,0,0,0}};
      #pragma unroll
      for (int kk = 0; kk < 4; ++kk) {
        bf16x8 b = *(const bf16x8*)(WP + (nt * 16 + m) * 128 + kk * 32 + q * 8);
        #pragma unroll
        for (int mt = 0; mt < 2; ++mt)
          acc[mt] = __builtin_amdgcn_mfma_f32_16x16x32_bf16(a[mt][kk], b, acc[mt], 0, 0, 0);
      }
      #pragma unroll
      for (int mt = 0; mt < 2; ++mt)
        #pragma unroll
        for (int r = 0; r < 4; ++r) {
          int row = mt * 16 + q * 4 + r;
          float v = acc[mt][r];
          xzl[row * 520 + n] = shof(f2b(n < 256 ? v : silu(v)));
        }
    }
  }
  __syncthreads();
  {  // xz coalesced copy-out
    #pragma unroll
    for (int k = 0; k < 4; ++k) {
      int chunk = tid + k * 512;
      int row = chunk >> 6, seg = chunk & 63;
      uint4 v = *(const uint4*)&xzl[row * 520 + seg * 8];
      int n0 = seg * 8;
      if (n0 < 256) *(uint4*)(xpre + (tok0 + row) * 256 + n0) = v;
      else          *(uint4*)(siluz + (tok0 + row) * 256 + (n0 - 256)) = v;
    }
  }
}

// ---------------- conv (depthwise w4 + silu) + x_proj MFMA -> xc, xdbl ----------------
__global__ __launch_bounds__(256) void conv_k(
    const bf16* __restrict__ xpre, const void* __restrict__ cw, const void* __restrict__ cb,
    const float* __restrict__ wsf, bf16* __restrict__ xc, float* __restrict__ xdbl,
    const int* __restrict__ flagp)
{
  __shared__ short xh[35 * 256];
  __shared__ short cs[32 * 264];
  const int f = *flagp;
  const int tid = threadIdx.x;
  const int tok0 = blockIdx.x * 32;
  const bool seqstart = (tok0 & (SEQ - 1)) == 0;
  for (int c = tid; c < 1120; c += 256) {
    int e0 = c * 8;
    int tt = e0 >> 8, i = e0 & 255;
    int gtok = tok0 + tt - 3;
    uint4* dst = (uint4*)(xh + e0);
    if (gtok >= 0 && !(seqstart && tt < 3)) *dst = *(const uint4*)(xpre + gtok * 256 + i);
    else                                    *dst = make_uint4(0, 0, 0, 0);
  }
  __syncthreads();
  {
    const int ch0 = (tid & 63) * 4;
    const int t0 = (tid >> 6) * 8;
    float w4[4][4], cb4[4];
    #pragma unroll
    for (int c = 0; c < 4; ++c) {
      cb4[c] = ldin(cb, ch0 + c, f);
      #pragma unroll
      for (int k = 0; k < 4; ++k) w4[c][k] = ldin(cw, (ch0 + c) * 4 + k, f);
    }
    float win[11][4];
    #pragma unroll
    for (int r = 0; r < 11; ++r) {
      uint2 v = *(const uint2*)&xh[(t0 + r) * 256 + ch0];
      win[r][0] = lo16f(v.x); win[r][1] = hi16f(v.x);
      win[r][2] = lo16f(v.y); win[r][3] = hi16f(v.y);
    }
    #pragma unroll
    for (int t = 0; t < 8; ++t) {
      unsigned pk[2];
      #pragma unroll
      for (int cp = 0; cp < 2; ++cp) {
        float o[2];
        #pragma unroll
        for (int ci = 0; ci < 2; ++ci) {
          int c = cp * 2 + ci;
          float acc = cb4[c];
          #pragma unroll
          for (int k = 0; k < 4; ++k) acc = fmaf(win[t + k][c], w4[c][k], acc);
          o[ci] = silu(acc);
        }
        pk[cp] = pack2(o[0], o[1]);
      }
      uint2 pv = make_uint2(pk[0], pk[1]);
      *(uint2*)&cs[(t0 + t) * 264 + ch0] = pv;
      *(uint2*)(xc + (tok0 + t0 + t) * 256 + ch0) = pv;
    }
  }
  __syncthreads();
  const int w = tid >> 6;
  if (w < 2) {
    const bf16* Wx = (const bf16*)(wsf + OFF_WB) + WB_XP;
    const int lane = tid & 63, m = lane & 15, quad = lane >> 4;
    f32x4 acc[3] = {{0,0,0,0},{0,0,0,0},{0,0,0,0}};
    #pragma unroll
    for (int k0 = 0; k0 < 256; k0 += 32) {
      bf16x8 af = *(const bf16x8*)&cs[(w * 16 + m) * 264 + k0 + quad * 8];
      #pragma unroll
      for (int nt = 0; nt < 3; ++nt) {
        bf16x8 bfr = *(const bf16x8*)(Wx + (nt * 16 + m) * 256 + k0 + quad * 8);
        acc[nt] = __builtin_amdgcn_mfma_f32_16x16x32_bf16(af, bfr, acc[nt], 0, 0, 0);
      }
    }
    #pragma unroll
    for (int nt = 0; nt < 3; ++nt) {
      int n = nt * 16 + m;
      if (n < 40) {
        #pragma unroll
        for (int r = 0; r < 4; ++r)
          xdbl[(tok0 + w * 16 + quad * 4 + r) * 40 + n] = acc[nt][r];
      }
    }
  }
}

// ---------------- scan pass F: chunk summaries only (pure scan_k<false>, R8-verified) ----------------
__global__ __launch_bounds__(256) void scanF_k(
    const float* __restrict__ xdbl, const bf16* __restrict__ xc,
    const void* __restrict__ A_log, const void* __restrict__ dt_b,
    const float* __restrict__ WDT, float* __restrict__ summ, const int* __restrict__ flagp)
{
  const int f = *flagp;
  const int tid = threadIdx.x;
  const int bb = blockIdx.x >> 2, dgsup = blockIdx.x & 3, c = blockIdx.y;
  const int dgsub = tid >> 6, lane = tid & 63, dl = lane >> 2, squad = lane & 3;
  const int dg = dgsup * 4 + dgsub;
  const int bxOld = bb * 16 + dg;
  const int d_comp = dg * 16 + dl;
  const int bd = tid & 63;
  const int d_stg = dgsup * 64 + bd;
  const int bdc = dgsub * 16 + dl;
  const int tok_base = bb * SEQ + c * NCH;

  __shared__ float dt_l[NCH * 8];     // 1 KB
  __shared__ float dx_l[16 * 64 * 2]; // 8 KB
  __shared__ float Bp[16 * 16];       // 1 KB

  float Aval2[4];
  #pragma unroll
  for (int j = 0; j < 4; ++j)
    Aval2[j] = -__expf(ldin(A_log, d_comp * 16 + squad * 4 + j, f)) * LOG2E;
  const float dtb_stg = ldin(dt_b, d_stg, f);
  float wdt[8];
  #pragma unroll
  for (int r = 0; r < 8; ++r) wdt[r] = WDT[r * 256 + d_stg];

  float h[4] = {0.f, 0.f, 0.f, 0.f};
  float sdlt = 0.f;

  if (tid < 64)   // dt_l: whole chunk, [t][8]; 2 threads/token
    *(float4*)(dt_l + tid * 4) = *(const float4*)(xdbl + (tok_base + (tid >> 1)) * 40 + (tid & 1) * 4);

  #pragma unroll 1
  for (int half = 0; half < 2; ++half) {
    const int tb = half * 16;
    __syncthreads();   // prev half done; dt_l ready for half 0
    {   // B plane: [t-half][s], 16 tok x 16 s
      int tl = tid >> 4, s = tid & 15;
      Bp[tid] = xdbl[(tok_base + tb + tl) * 40 + 8 + s];
    }
    #pragma unroll
    for (int k = 0; k < 4; ++k) {   // dx: [t-half][bd]
      int tl = (tid >> 6) + k * 4;
      int tok = tok_base + tb + tl;
      const float* dtr = dt_l + (tb + tl) * 8;
      float a = dtb_stg;
      #pragma unroll
      for (int r = 0; r < 8; ++r) a = fmaf(dtr[r], wdt[r], a);
      float dlt = softplus(a);
      float xcv = b2f(xc[tok * 256 + d_stg]);
      *(float2*)(dx_l + (tl * 64 + bd) * 2) = make_float2(dlt, dlt * xcv);
    }
    __syncthreads();

    #pragma unroll 8
    for (int tl = 0; tl < 16; ++tl) {
      float2 dx = *(const float2*)(dx_l + (tl * 64 + bdc) * 2);   // quad-broadcast
      float4 B4 = *(const float4*)(Bp + tl * 16 + squad * 4);
      float Bv[4] = {B4.x, B4.y, B4.z, B4.w};
      #pragma unroll
      for (int j = 0; j < 4; ++j) {
        float dA = exp2f_fast(dx.x * Aval2[j]);
        h[j] = fmaf(dA, h[j], dx.y * Bv[j]);
      }
      sdlt += dx.x;
    }
  }

  float* dst = summ + ((bxOld * NCHUNK + c) * 256 + dl * 16 + squad * 4) * 2;
  *(float4*)(dst)     = make_float4(exp2f_fast(Aval2[0] * sdlt), h[0],
                                    exp2f_fast(Aval2[1] * sdlt), h[1]);
  *(float4*)(dst + 4) = make_float4(exp2f_fast(Aval2[2] * sdlt), h[2],
                                    exp2f_fast(Aval2[3] * sdlt), h[3]);
}

// phase B: exclusive scan over chunk summaries, 16-deep load batching
__global__ __launch_bounds__(256) void scanB_k(const float* __restrict__ summ, float* __restrict__ hinit) {
  int bx = blockIdx.x, qq = threadIdx.x;
  float h = 0.f;
  for (int c0 = 0; c0 < NCHUNK; c0 += 16) {
    float2 sv[16];
    #pragma unroll
    for (int k = 0; k < 16; ++k)
      sv[k] = *(const float2*)(summ + ((bx * NCHUNK + c0 + k) * 256 + qq) * 2);
    #pragma unroll
    for (int k = 0; k < 16; ++k) {
      hinit[(bx * NCHUNK + c0 + k) * 256 + qq] = h;
      h = fmaf(sv[k].x, h, sv[k].y);
    }
  }
}

// ---------------- backC: chain-replay scan (g in LDS) + m GEMM + rms2/gate + out GEMM ----------------
// Replaces R9's ploc/cumd parallel correction with the R7/R8-verified chain replay from hinit:
// no ploc/cumd buffers (saves 67 MB of HBM traffic). 2 channel-passes x 2 token-halves.
__global__ __launch_bounds__(512) void backC_k(
    const float* __restrict__ xdbl, const bf16* __restrict__ xc, const bf16* __restrict__ siluz,
    const void* __restrict__ A_log, const void* __restrict__ D_par, const void* __restrict__ dt_b,
    const float* __restrict__ WDT, const float* __restrict__ hinit,
    const float* __restrict__ wsf, const void* __restrict__ w2,
    const bf16* __restrict__ u, const bf16* __restrict__ wsw, const void* __restrict__ b_op,
    const void* __restrict__ x, void* __restrict__ out, const int* __restrict__ flagp)
{
  // gl [0,16896): bf16[32][264]. Bp [16896,18944): f32[32][16]. Cp [18944,20992): f32[32][16].
  // dt_l [20992,22016): f32[32][8]. dx_l [22016,38400): f32[16][128][2]. gcl [38400,46592): f32[16][128].
  // ms (8704 B) aliases dx_l region after the scan part; outl aliases ms.
  __shared__ __align__(16) char smem[46592];
  short* gl   = (short*)smem;
  float* Bp   = (float*)(smem + 16896);
  float* Cp   = (float*)(smem + 18944);
  float* dt_l = (float*)(smem + 20992);
  float* dx_l = (float*)(smem + 22016);
  float* gcl  = (float*)(smem + 38400);
  short* ms   = (short*)(smem + 22016);

  const int f = *flagp;
  const int tid = threadIdx.x;
  const int tok0 = blockIdx.x * 32;
  const int bb = tok0 >> 12;                  // /SEQ
  const int c  = (tok0 & (SEQ - 1)) >> 5;     // /NCH
  const int w = tid >> 6, lane = tid & 63;
  const int dl = lane >> 2, squad = lane & 3;
  const int chL = w * 16 + dl;                // 0..127 compute channel-within-pass
  const int chE = tid & 127;                  // staging channel-within-pass

  {  // stage B/C planes (channel-independent): 32 tok x 16 s, one elem per thread
    int tl = tid >> 4, s = tid & 15;
    Bp[tid] = xdbl[(tok0 + tl) * 40 + 8 + s];
    Cp[tid] = xdbl[(tok0 + tl) * 40 + 24 + s];
  }
  if (tid < 64)   // dt_l: [t][8], 2 threads/token
    *(float4*)(dt_l + tid * 4) = *(const float4*)(xdbl + (tok0 + (tid >> 1)) * 40 + (tid & 1) * 4);

  #pragma unroll 1
  for (int p = 0; p < 2; ++p) {
    const int ch  = p * 128 + chL;
    const int gch = p * 128 + chE;
    float Aval2[4];
    #pragma unroll
    for (int j = 0; j < 4; ++j)
      Aval2[j] = -__expf(ldin(A_log, ch * 16 + squad * 4 + j, f)) * LOG2E;
    const float dtb = ldin(dt_b, gch, f);
    float wdt[8];
    #pragma unroll
    for (int r = 0; r < 8; ++r) wdt[r] = WDT[r * 256 + gch];
    float4 hv = *(const float4*)(hinit +
        ((bb * 16 + (ch >> 4)) * NCHUNK + c) * 256 + (ch & 15) * 16 + squad * 4);
    float h[4] = {hv.x, hv.y, hv.z, hv.w};

    #pragma unroll 1
    for (int half = 0; half < 2; ++half) {
      const int tb = half * 16;
      __syncthreads();   // staging visible (first) / prev-half dx & gcl reads done
      #pragma unroll
      for (int k = 0; k < 4; ++k) {   // dx: 16 tok x 128 ch, 4 per thread
        int tl = (tid >> 7) + k * 4;
        int tok = tok0 + tb + tl;
        const float* dtr = dt_l + (tb + tl) * 8;
        float a = dtb;
        #pragma unroll
        for (int r = 0; r < 8; ++r) a = fmaf(dtr[r], wdt[r], a);
        float dlt = softplus(a);
        float xcv = b2f(xc[tok * 256 + gch]);
        *(float2*)(dx_l + (tl * 128 + chE) * 2) = make_float2(dlt, dlt * xcv);
      }
      __syncthreads();

      #pragma unroll 8
      for (int tl = 0; tl < 16; ++tl) {
        float2 dx = *(const float2*)(dx_l + (tl * 128 + chL) * 2);   // quad-broadcast
        float4 B4 = *(const float4*)(Bp + (tb + tl) * 16 + squad * 4);
        float Bv[4] = {B4.x, B4.y, B4.z, B4.w};
        #pragma unroll
        for (int j = 0; j < 4; ++j) {
          float dA = exp2f_fast(dx.x * Aval2[j]);
          h[j] = fmaf(dA, h[j], dx.y * Bv[j]);
        }
        float4 C4 = *(const float4*)(Cp + (tb + tl) * 16 + squad * 4);
        float pv = h[0] * C4.x;
        pv = fmaf(h[1], C4.y, pv);
        pv = fmaf(h[2], C4.z, pv);
        pv = fmaf(h[3], C4.w, pv);
        pv = dpp_add<0xB1>(pv);   // quad xor1
        pv = dpp_add<0x4E>(pv);   // quad xor2
        if (squad == 0) gcl[tl * 128 + chL] = pv;
      }
      __syncthreads();
      {  // g epilogue for this half -> gl tile
        const float Dp = ldin(D_par, gch, f);
        #pragma unroll
        for (int k = 0; k < 4; ++k) {
          int tl = (tid >> 7) + k * 4;
          int tok = tok0 + tb + tl;
          float pf = gcl[tl * 128 + chE];
          float xcv = b2f(xc[tok * 256 + gch]);
          gl[(tb + tl) * 264 + gch] = shof(f2b((pf + xcv * Dp) * b2f(siluz[tok * 256 + gch])));
        }
      }
    }
  }
  __syncthreads();   // gl complete; dx_l/gcl dead -> ms alias safe after phase-1 writes

  const int m = lane & 15, q = lane >> 4;
  const bf16* WM = (const bf16*)(wsf + OFF_WB) + WB_MO;
  const bf16* WO = (const bf16*)(wsf + OFF_WB) + WB_OP;
  {  // phase 1: m = g@Wmo^T (K=256, N=128); wave w -> nt w; g from LDS
    f32x4 acc[2] = {{0,0,0,0},{0,0,0,0}};
    #pragma unroll
    for (int kk = 0; kk < 8; ++kk) {
      bf16x8 a0 = *(const bf16x8*)&gl[m * 264 + kk * 32 + q * 8];
      bf16x8 a1 = *(const bf16x8*)&gl[(16 + m) * 264 + kk * 32 + q * 8];
      int nt = w;
      bf16x8 b = *(const bf16x8*)(WM + (nt * 16 + m) * 256 + kk * 32 + q * 8);
      acc[0] = __builtin_amdgcn_mfma_f32_16x16x32_bf16(a0, b, acc[0], 0, 0, 0);
      acc[1] = __builtin_amdgcn_mfma_f32_16x16x32_bf16(a1, b, acc[1], 0, 0, 0);
    }
    {
      int n = w * 16 + m;
      #pragma unroll
      for (int mt = 0; mt < 2; ++mt)
        #pragma unroll
        for (int r = 0; r < 4; ++r)
          ms[(mt * 16 + q * 4 + r) * 136 + n] = shof(f2b(acc[mt][r]));
    }
  }
  __syncthreads();
  {  // rms2 + u residual + wsw gate (16 threads/token, 8 ch each)
    const int token = tid >> 4, r = tid & 15;
    float mv[8]; float ss = 0.f;
    #pragma unroll
    for (int k = 0; k < 8; ++k) {
      mv[k] = b2f(((const bf16*)ms)[token * 136 + r * 8 + k]);
      ss += mv[k] * mv[k];
    }
    ss += __shfl_xor(ss, 1, 16); ss += __shfl_xor(ss, 2, 16);
    ss += __shfl_xor(ss, 4, 16); ss += __shfl_xor(ss, 8, 16);
    float sc = rsqrtf(ss * (1.f / 128.f) + EPS);
    #pragma unroll
    for (int k = 0; k < 8; ++k) {
      int i = r * 8 + k;
      int ga = (tok0 + token) * 128 + i;
      float v = mv[k] * sc * ldin(w2, i, f) + b2f(u[ga]);
      ms[token * 136 + i] = shof(f2b(v * b2f(wsw[ga])));
    }
  }
  __syncthreads();
  {  // phase 2: out = ms@Wop^T + b_op + resid (K=128, N=64); wave w -> (mt = w>>2, nt = w&3)
    const int mt = w >> 2, nt = w & 3;
    bf16x8 a[4];
    #pragma unroll
    for (int kk = 0; kk < 4; ++kk)
      a[kk] = *(const bf16x8*)&ms[(mt * 16 + m) * 136 + kk * 32 + q * 8];
    __syncthreads();   // all ms reads done; outl alias becomes safe
    f32x4 acc = {0,0,0,0};
    #pragma unroll
    for (int kk = 0; kk < 4; ++kk) {
      bf16x8 b = *(const bf16x8*)(WO + (nt * 16 + m) * 128 + kk * 32 + q * 8);
      acc = __builtin_amdgcn_mfma_f32_16x16x32_bf16(a[kk], b, acc, 0, 0, 0);
    }
    float* outl = (float*)ms;   // [32][68]
    int n = nt * 16 + m;
    #pragma unroll
    for (int r = 0; r < 4; ++r)
      outl[(mt * 16 + q * 4 + r) * 68 + n] = acc[r];
  }
  __syncthreads();
  {  // coalesced copy-out with bias + residual
    const float* outl = (const float*)ms;
    int row = tid >> 4, c0 = (tid & 15) * 4;
    float v[4];
    #pragma unroll
    for (int j = 0; j < 4; ++j)
      v[j] = outl[row * 68 + c0 + j] + ldin(b_op, c0 + j, f)
           + ldin(x, (tok0 + row) * 64 + c0 + j, f);
    if (f) {
      *(float4*)((float*)out + (tok0 + row) * 64 + c0) = make_float4(v[0], v[1], v[2], v[3]);
    } else {
      uint2 pv = make_uint2(pack2(v[0], v[1]), pack2(v[2], v[3]));
      *(uint2*)((bf16*)out + (tok0 + row) * 64 + c0) = pv;
    }
  }
}

// ---------------- launch ----------------
extern "C" void kernel_launch(void* const* d_in, const int* in_sizes, int n_in,
                              void* d_out, int out_size, void* d_ws, size_t ws_size,
                              hipStream_t stream) {
  (void)in_sizes; (void)n_in; (void)out_size; (void)ws_size;
  const void* x        = d_in[0];
  const void* w_norm1  = d_in[1];
  const void* w_norm2  = d_in[2];
  const void* W_ip     = d_in[3];
  const void* b_ip     = d_in[4];
  const void* W_fp     = d_in[5];
  const void* b_fp     = d_in[6];
  const void* W_wp     = d_in[7];
  const void* b_wp     = d_in[8];
  const void* W_op     = d_in[9];
  const void* b_op     = d_in[10];
  const void* in_proj  = d_in[11];
  const void* conv_w   = d_in[12];
  const void* conv_b   = d_in[13];
  const void* x_proj   = d_in[14];
  const void* dt_projw = d_in[15];
  const void* dt_projb = d_in[16];
  const void* A_log    = d_in[17];
  const void* D_par    = d_in[18];
  const void* mo_w     = d_in[19];

  float* wsf    = (float*)d_ws;
  float* xdbl   = wsf + OFF_XDBL;
  bf16*  wsw_b  = (bf16*)(wsf + OFF_WSW);
  bf16*  u_b    = (bf16*)(wsf + OFF_U);
  bf16*  xpre_b = (bf16*)(wsf + OFF_R2);
  float* summ   = wsf + OFF_SUMM;
  float* hin    = wsf + OFF_HIN;
  bf16*  siluz_b= (bf16*)(wsf + OFF_SILUZ);
  bf16*  xc_b   = (bf16*)(wsf + OFF_XC);
  int*   flagp  = (int*)(wsf + OFF_FLAG);

  prep_k<<<dim3(592), dim3(256), 0, stream>>>(W_ip, W_wp, W_fp, in_proj, mo_w, W_op,
                                              x_proj, dt_projw, x, wsf, flagp);
  fm_k<<<dim3(NTOK / 32), dim3(512), 0, stream>>>(x, w_norm1, wsf, b_ip, b_wp, b_fp,
                                                  wsw_b, u_b, xpre_b, siluz_b, flagp);
  conv_k<<<dim3(NTOK / 32), dim3(256), 0, stream>>>(xpre_b, conv_w, conv_b, wsf, xc_b, xdbl, flagp);
  scanF_k<<<dim3(16, NCHUNK), dim3(256), 0, stream>>>(xdbl, xc_b, A_log, dt_projb,
                                                      wsf + OFF_WDT, summ, flagp);
  scanB_k<<<dim3(64), dim3(256), 0, stream>>>(summ, hin);
  backC_k<<<dim3(NTOK / 32), dim3(512), 0, stream>>>(xdbl, xc_b, siluz_b, A_log, D_par,
                                                     dt_projb, wsf + OFF_WDT, hin, wsf, w_norm2,
                                                     u_b, wsw_b, b_op, x, d_out, flagp);
}